// Round 14
// baseline (2487.107 us; speedup 1.0000x reference)
//
#include <hip/hip_runtime.h>
#include <stdint.h>

#define B_   8
#define S_   1024
#define IND  256
#define D_   1024
#define H_   16
#define DKH  64
#define L_   6
#define FF   4096
#define NTOK (B_*S_)

typedef __bf16 bf16;
typedef __attribute__((ext_vector_type(4))) float  f32x4;
typedef __attribute__((ext_vector_type(8))) __bf16 bf16x8;
typedef __attribute__((ext_vector_type(4))) __bf16 bf16x4;
typedef __attribute__((ext_vector_type(2))) __bf16 bf16x2;

#define AS1 __attribute__((address_space(1)))
#define AS3 __attribute__((address_space(3)))

__device__ __forceinline__ void gload16(const void* g, void* l) {
  __builtin_amdgcn_global_load_lds((AS1 void*)(const_cast<void*>(g)), (AS3 void*)l, 16, 0, 0);
}

// ---------------- weight transpose+convert: in [K][N] f32 -> out [N][K] bf16 ----------------
__global__ __launch_bounds__(256)
void k_trans(const float* __restrict__ in, bf16* __restrict__ out,
             int K, int N, long inStride, long outStride) {
  __shared__ float t[64][65];
  const float* inp = in + (long)blockIdx.z * inStride;
  bf16* outp = out + (long)blockIdx.z * outStride;
  const int n0 = blockIdx.x * 64, k0 = blockIdx.y * 64;
  const int r = threadIdx.x >> 4;
  const int c4 = (threadIdx.x & 15) * 4;
  #pragma unroll
  for (int j = 0; j < 64; j += 16) {
    f32x4 v = *(const f32x4*)(inp + (long)(k0 + r + j) * N + n0 + c4);
    #pragma unroll
    for (int i = 0; i < 4; ++i) t[r + j][c4 + i] = v[i];
  }
  __syncthreads();
  #pragma unroll
  for (int j = 0; j < 64; j += 16) {
    const int n = r + j;
    bf16x4 o;
    #pragma unroll
    for (int i = 0; i < 4; ++i) o[i] = (bf16)t[c4 + i][n];
    *(bf16x4*)(outp + (long)(n0 + n) * K + k0 + c4) = o;
  }
}

// ---------------- fp32 -> bf16 elementwise ----------------
__global__ __launch_bounds__(256)
void k_f2b(const float* __restrict__ in, bf16* __restrict__ out) {
  const long i = ((long)blockIdx.x * 256 + threadIdx.x) * 4;
  f32x4 v = *(const f32x4*)(in + i);
  bf16x4 o;
  #pragma unroll
  for (int j = 0; j < 4; ++j) o[j] = (bf16)v[j];
  *(bf16x4*)(out + i) = o;
}

// ---------------- positional encoding rows ----------------
__global__ __launch_bounds__(256)
void k_pe(float* __restrict__ pe) {
  const int i = blockIdx.x * 256 + threadIdx.x;
  const int b = i >> 10, d = i & 1023;
  const float k2 = (float)(d & ~1);
  const float dv = __expf(k2 * (-9.210340371976184f / (float)D_));
  const float a = (float)b * dv;
  pe[i] = (d & 1) ? cosf(a) : sinf(a);
}

// ---------------- pack per-layer qkv bias [L][3072] ----------------
__global__ __launch_bounds__(256)
void k_packb(const float* __restrict__ bq, const float* __restrict__ bk,
             const float* __restrict__ bv, float* __restrict__ out) {
  const int i = blockIdx.x * 256 + threadIdx.x;
  const int l = i / 3072, j = i % 3072;
  const float* src = (j < 1024) ? bq : ((j < 2048) ? bk : bv);
  out[i] = src[l * 1024 + (j & 1023)];
}

// ---------------- 128^2 GEMM — embedding (EPI 3: +pe, bf16 out) ----------------
template<int EPI>
__global__ __launch_bounds__(256)
void k_gemm(const bf16* __restrict__ A, const bf16* __restrict__ Bt,
            const float* __restrict__ bias,
            void* __restrict__ out0, void* __restrict__ out1,
            const float* __restrict__ pe,
            int M, int N, int K) {
  __shared__ __align__(16) bf16 sA[128 * 32];
  __shared__ __align__(16) bf16 sB[128 * 32];
  const int tid = threadIdx.x;
  const int lane = tid & 63, wv = tid >> 6;
  const int bx = blockIdx.x, by = blockIdx.y;
  const int wm = wv >> 1, wn = wv & 1;
  const int lg = lane >> 4, lc = lane & 15;
  const long arow0 = (long)by * 128;
  const long brow0 = (long)bx * 128;
  const int c0 = (wv * 2 + 0) * 64 + lane;
  const int c1 = (wv * 2 + 1) * 64 + lane;
  const int r0 = c0 >> 2, s0 = c0 & 3;
  const int r1 = c1 >> 2, s1 = c1 & 3;
  bf16* ldsA0 = sA + (wv * 2 + 0) * 512;
  bf16* ldsA1 = sA + (wv * 2 + 1) * 512;
  bf16* ldsB0 = sB + (wv * 2 + 0) * 512;
  bf16* ldsB1 = sB + (wv * 2 + 1) * 512;
  const bf16* Ab = A + arow0 * K;
  const bf16* Bb = Bt + brow0 * K;
  f32x4 acc[4][4] = {};
  const int kT = K >> 5;
  for (int kt = 0; kt < kT; ++kt) {
    const int k0 = kt << 5;
    gload16(Ab + (long)r0 * K + k0 + s0 * 8, ldsA0);
    gload16(Ab + (long)r1 * K + k0 + s1 * 8, ldsA1);
    gload16(Bb + (long)r0 * K + k0 + s0 * 8, ldsB0);
    gload16(Bb + (long)r1 * K + k0 + s1 * 8, ldsB1);
    __syncthreads();
    bf16x8 af[4], bfr[4];
    #pragma unroll
    for (int mr = 0; mr < 4; ++mr)
      af[mr] = *(const bf16x8*)(sA + (wm * 64 + mr * 16 + lc) * 32 + lg * 8);
    #pragma unroll
    for (int nc = 0; nc < 4; ++nc)
      bfr[nc] = *(const bf16x8*)(sB + (wn * 64 + nc * 16 + lc) * 32 + lg * 8);
    #pragma unroll
    for (int mr = 0; mr < 4; ++mr)
      #pragma unroll
      for (int nc = 0; nc < 4; ++nc)
        acc[mr][nc] = __builtin_amdgcn_mfma_f32_16x16x32_bf16(af[mr], bfr[nc], acc[mr][nc], 0, 0, 0);
    __syncthreads();
  }
  #pragma unroll
  for (int mr = 0; mr < 4; ++mr) {
    const int row0 = by * 128 + wm * 64 + mr * 16 + lg * 4;
    #pragma unroll
    for (int nc = 0; nc < 4; ++nc) {
      const int col = bx * 128 + wn * 64 + nc * 16 + lc;
      const float bvv = bias[col];
      #pragma unroll
      for (int r = 0; r < 4; ++r) {
        float v = acc[mr][nc][r] + bvv;
        const long rr = row0 + r;
        if constexpr (EPI == 0) {
          ((bf16*)out0)[rr * N + col] = (bf16)v;
        } else {
          const long bb = rr >> 10;
          v += pe[bb * D_ + col];
          ((bf16*)out1)[rr * N + col] = (bf16)v;
        }
      }
    }
  }
}

// ---------------- 256^2 8-phase GEMM (R5 schedule — banked best) ----------------
template<int EPI, int SPLIT>
__global__ __launch_bounds__(512, 2)
void k_gemm256(const bf16* __restrict__ A, const bf16* __restrict__ Bt,
               const float* __restrict__ bias,
               void* __restrict__ out0, void* __restrict__ out1,
               bf16* __restrict__ pout0, bf16* __restrict__ pout1,
               int M, int N, int K) {
  __shared__ __align__(16) bf16 lds[65536];
  const int tid = threadIdx.x;
  const int lane = tid & 63, wv = tid >> 6;
  const int wm = wv >> 2, wn = wv & 3;
  const int lg = lane >> 4, lc = lane & 15;
  const int gx = gridDim.x;
  const int nwg = gx * gridDim.y;
  int bid = blockIdx.x + blockIdx.y * gx;
  const int cpx = nwg >> 3;
  bid = (bid & 7) * cpx + (bid >> 3);
  const int bxs = bid % gx, bys = bid / gx;
  const int tileRow = bys * 256, tileCol = bxs * 256;
  const int kPart = SPLIT ? (K >> 1) : K;
  const long kOff = SPLIT ? (long)blockIdx.z * kPart : 0;
  const bf16* Abase = A + (long)tileRow * K + kOff;
  const bf16* Bbase = Bt + (long)tileCol * K + kOff;
  const long laneOff = (long)lc * K + lg * 8;
  f32x4 acc[8][4] = {};
  const int NT = kPart >> 6;
  const int NI = NT >> 1;

  auto stA = [&](int t, int h, int bb) {
    const int rg = h * 16 + wv * 2;
    const int mb = rg >> 1;
    const bf16* s = Abase + (long)(mb * 16) * K + t * 64 + laneOff;
    bf16* d = lds + bb * 32768 + rg * 512;
    gload16(s, d);
    gload16(s + 32, d + 512);
  };
  auto stB = [&](int t, int h, int bb) {
    const int rg = h * 16 + wv * 2;
    const int mb = rg >> 1;
    const bf16* s = Bbase + (long)(mb * 16) * K + t * 64 + laneOff;
    bf16* d = lds + bb * 32768 + 16384 + rg * 512;
    gload16(s, d);
    gload16(s + 32, d + 512);
  };

  bf16x8 aF[8];
  bf16x8 bF0[4], bF1[4];

#define LDA(BB, MH) do { _Pragma("unroll") for (int m = 0; m < 4; ++m) \
    _Pragma("unroll") for (int kk = 0; kk < 2; ++kk) \
      aF[m*2+kk] = *(const bf16x8*)(lds + (BB)*32768 + ((wm*8 + (MH)*4 + m)*2 + kk)*512 + lane*8); \
  } while(0)
#define LDB(BB, NH, DST) do { _Pragma("unroll") for (int n = 0; n < 2; ++n) \
    _Pragma("unroll") for (int kk = 0; kk < 2; ++kk) \
      DST[n*2+kk] = *(const bf16x8*)(lds + (BB)*32768 + 16384 + ((wn*4 + (NH)*2 + n)*2 + kk)*512 + lane*8); \
  } while(0)
#define MMA(MH, NH, BSRC) do { \
    __builtin_amdgcn_s_setprio(1); \
    _Pragma("unroll") for (int m = 0; m < 4; ++m) \
      _Pragma("unroll") for (int n = 0; n < 2; ++n) { \
        acc[(MH)*4+m][(NH)*2+n] = __builtin_amdgcn_mfma_f32_16x16x32_bf16(aF[m*2+0], BSRC[n*2+0], acc[(MH)*4+m][(NH)*2+n], 0, 0, 0); \
        acc[(MH)*4+m][(NH)*2+n] = __builtin_amdgcn_mfma_f32_16x16x32_bf16(aF[m*2+1], BSRC[n*2+1], acc[(MH)*4+m][(NH)*2+n], 0, 0, 0); \
      } \
    __builtin_amdgcn_s_setprio(0); \
  } while(0)
#define VM8 asm volatile("s_waitcnt vmcnt(8)" ::: "memory")
#define VM0 asm volatile("s_waitcnt vmcnt(0)" ::: "memory")
#define BAR __builtin_amdgcn_s_barrier()

  stA(0, 0, 0); stB(0, 0, 0); stA(0, 1, 0); stB(0, 1, 0);
  stA(1, 0, 1); stB(1, 0, 1); stA(1, 1, 1); stB(1, 1, 1);

  for (int i = 0; i < NI - 1; ++i) {
    const int t2 = 2 * i + 2, t3 = 2 * i + 3;
    VM8; BAR; LDA(0, 0); LDB(0, 0, bF0);   MMA(0, 0, bF0);
         BAR; LDB(0, 1, bF1); stA(t2, 0, 0);              MMA(0, 1, bF1);
         BAR; LDA(0, 1);      stB(t2, 0, 0);              MMA(1, 0, bF0);
         BAR; stA(t2, 1, 0);  stB(t2, 1, 0);              MMA(1, 1, bF1);
    VM8; BAR; LDA(1, 0); LDB(1, 0, bF0);   MMA(0, 0, bF0);
         BAR; LDB(1, 1, bF1); stA(t3, 0, 1);              MMA(0, 1, bF1);
         BAR; LDA(1, 1);      stB(t3, 0, 1);              MMA(1, 0, bF0);
         BAR; stA(t3, 1, 1);  stB(t3, 1, 1);              MMA(1, 1, bF1);
  }
  {
    VM8; BAR; LDA(0, 0); LDB(0, 0, bF0); MMA(0, 0, bF0);
         BAR; LDB(0, 1, bF1);            MMA(0, 1, bF1);
         BAR; LDA(0, 1);                 MMA(1, 0, bF0);
         BAR;                            MMA(1, 1, bF1);
    VM0; BAR; LDA(1, 0); LDB(1, 0, bF0); MMA(0, 0, bF0);
         BAR; LDB(1, 1, bF1);            MMA(0, 1, bF1);
         BAR; LDA(1, 1);                 MMA(1, 0, bF0);
         BAR;                            MMA(1, 1, bF1);
  }
#undef LDA
#undef LDB
#undef MMA
#undef VM8
#undef VM0
#undef BAR

  #pragma unroll
  for (int mr = 0; mr < 8; ++mr) {
    const int row0 = tileRow + wm * 128 + mr * 16 + lg * 4;
    #pragma unroll
    for (int nr = 0; nr < 4; ++nr) {
      const int col = tileCol + wn * 64 + nr * 16 + lc;
      if constexpr (SPLIT) {
        bf16* po = blockIdx.z ? pout1 : pout0;
        #pragma unroll
        for (int r = 0; r < 4; ++r)
          po[(long)(row0 + r) * N + col] = (bf16)acc[mr][nr][r];
      } else if constexpr (EPI == 2) {
        const float bvv = bias[col];
        const int which = col >> 10;
        const int hh = (col & 1023) >> 6;
        const int dk = col & 63;
        const long bb = row0 >> 10;
        const int sr = row0 & 1023;
        if (which == 2) {
          bf16x4 pk;
          #pragma unroll
          for (int r = 0; r < 4; ++r) pk[r] = (bf16)(acc[mr][nr][r] + bvv);
          *(bf16x4*)((bf16*)out1 + ((bb * H_ + hh) * (long)DKH + dk) * S_ + sr) = pk;
        } else {
          #pragma unroll
          for (int r = 0; r < 4; ++r) {
            float v = acc[mr][nr][r] + bvv;
            if (which == 0) v *= 0.125f;
            ((bf16*)out0)[(long)which * NTOK * D_ + ((bb * H_ + hh) * (long)S_ + sr + r) * DKH + dk] = (bf16)v;
          }
        }
      } else {
        const float bvv = bias[col];
        #pragma unroll
        for (int r = 0; r < 4; ++r) {
          float v = acc[mr][nr][r] + bvv;
          const long rr = row0 + r;
          if constexpr (EPI == 1) v = fmaxf(v, 0.f);
          ((bf16*)out0)[rr * N + col] = (bf16)v;
        }
      }
    }
  }
}

// ---------------- 128^2 GEMM, ring-3 LDS (48KB -> 3 blocks/CU), vmcnt(4) prefetch ----------------
// 256 threads = 4 waves (2m x 2n), per-wave 64x64, acc[4][4] (~64 acc regs -> 3 waves/SIMD).
// Ring slot = 16KB (A 8KB | B 8KB); region = 16 rows x 32 k = 1024B, chunk==lane (conflict-free
// ds_read_b128 at region+lane*16; staging via pre-swizzled global source, linear LDS dest).
// Interval t: reads buf[t%3], stages tile t+2 -> buf[(t+2)%3] (= buffer last read at t-1,
// sealed by BAR_t). Per-wave vmcnt before the rendezvous BAR makes all waves' stages visible.
template<int EPI>
__global__ __launch_bounds__(256)
void k_g128(const bf16* __restrict__ A, const bf16* __restrict__ Bt,
            const float* __restrict__ bias,
            bf16* __restrict__ out0,
            int M, int N, int K) {
  __shared__ __align__(16) bf16 lds[24576];   // 48 KiB = 3 x (A 4096 | B 4096)
  const int tid = threadIdx.x, lane = tid & 63, wv = tid >> 6;
  const int wm = wv >> 1, wn = wv & 1;
  const int lg = lane >> 4, lc = lane & 15;
  const int gx = gridDim.x;
  const int nwg = gx * gridDim.y;
  int bid = blockIdx.x + blockIdx.y * gx;
  const int cpx = nwg >> 3;
  bid = (bid & 7) * cpx + (bid >> 3);
  const int bxs = bid % gx, bys = bid / gx;
  const int tileRow = bys * 128, tileCol = bxs * 128;
  const bf16* Abase = A + (long)tileRow * K;
  const bf16* Bbase = Bt + (long)tileCol * K;
  const long laneOff = (long)lc * K + lg * 8;
  f32x4 acc[4][4] = {};
  const int NT = K >> 5;        // BK = 32
  const int rg = wv * 2;        // this wave stages regions {rg, rg+1} of A and B

  auto stage = [&](int t, int b) {
    const bf16* sa = Abase + (long)(rg * 16) * K + t * 32 + laneOff;
    const bf16* sb = Bbase + (long)(rg * 16) * K + t * 32 + laneOff;
    bf16* base = lds + b * 8192;
    gload16(sa,                base + rg * 512);
    gload16(sa + (long)16 * K, base + rg * 512 + 512);
    gload16(sb,                base + 4096 + rg * 512);
    gload16(sb + (long)16 * K, base + 4096 + rg * 512 + 512);
  };

  stage(0, 0);
  stage(1, 1);
  int cur = 0;
  for (int t = 0; t < NT; ++t) {
    if (t < NT - 1) asm volatile("s_waitcnt vmcnt(4)" ::: "memory");
    else            asm volatile("s_waitcnt vmcnt(0)" ::: "memory");
    __builtin_amdgcn_s_barrier();
    const bf16* bufp = lds + cur * 8192;
    bf16x8 aF[4], bF[4];
    #pragma unroll
    for (int mr = 0; mr < 4; ++mr)
      aF[mr] = *(const bf16x8*)(bufp + (wm * 4 + mr) * 512 + lane * 8);
    #pragma unroll
    for (int nc = 0; nc < 4; ++nc)
      bF[nc] = *(const bf16x8*)(bufp + 4096 + (wn * 4 + nc) * 512 + lane * 8);
    if (t + 2 < NT) {
      int b2 = cur + 2; if (b2 >= 3) b2 -= 3;
      stage(t + 2, b2);
    }
    __builtin_amdgcn_s_setprio(1);
    #pragma unroll
    for (int mr = 0; mr < 4; ++mr)
      #pragma unroll
      for (int nc = 0; nc < 4; ++nc)
        acc[mr][nc] = __builtin_amdgcn_mfma_f32_16x16x32_bf16(aF[mr], bF[nc], acc[mr][nc], 0, 0, 0);
    __builtin_amdgcn_s_setprio(0);
    cur = (cur + 1 == 3) ? 0 : cur + 1;
  }

  #pragma unroll
  for (int mr = 0; mr < 4; ++mr) {
    const int row0 = tileRow + wm * 64 + mr * 16 + lg * 4;
    #pragma unroll
    for (int nc = 0; nc < 4; ++nc) {
      const int col = tileCol + wn * 64 + nc * 16 + lc;
      const float bvv = bias[col];
      #pragma unroll
      for (int r = 0; r < 4; ++r) {
        float v = acc[mr][nc][r] + bvv;
        if constexpr (EPI == 1) v = fmaxf(v, 0.f);
        out0[(long)(row0 + r) * N + col] = (bf16)v;
      }
    }
  }
}

// ---------------- flash attention (XCD-swizzled) ----------------
__global__ __launch_bounds__(256)
void k_flash(const bf16* __restrict__ qg, const bf16* __restrict__ kgl,
             const bf16* __restrict__ vtg, bf16* __restrict__ og) {
  __shared__ __align__(16) bf16 sK[64 * 64];
  __shared__ __align__(16) bf16 sV[64 * 64];
  __shared__ __align__(16) bf16 sP[4 * 16 * 64];
  const int tid = threadIdx.x, lane = tid & 63, wv = tid >> 6;
  const int lg = lane >> 4, lc = lane & 15;
  int bid = blockIdx.x + blockIdx.y * 16;
  bid = (bid & 7) * 256 + (bid >> 3);
  const int qt = bid & 15, bh = bid >> 4;
  const long base = (long)bh * S_ * DKH;
  const bf16* qb = qg + base;
  const bf16* kb = kgl + base;
  const bf16* vb = vtg + base;
  const int qrow = qt * 64 + wv * 16 + lc;
  const bf16x8 qf0 = *(const bf16x8*)(qb + (long)qrow * DKH + lg * 8);
  const bf16x8 qf1 = *(const bf16x8*)(qb + (long)qrow * DKH + 32 + lg * 8);
  float mrun = -3e38f, lrun = 0.f;
  f32x4 oacc[4] = {};
  bf16* sPw = sP + wv * (16 * 64);
  const int swzP = (lc & 7) << 4;
  const int c0 = wv * 128 + lane, c1 = c0 + 64;
  const int r0 = c0 >> 3, sl0 = (c0 & 7) ^ (r0 & 7);
  const int r1 = c1 >> 3, sl1 = (c1 & 7) ^ (r1 & 7);
  bf16* dst0 = sK + c0 * 8 - lane * 8;
  bf16* dst1 = sK + c1 * 8 - lane * 8;
  bf16* dstV0 = sV + c0 * 8 - lane * 8;
  bf16* dstV1 = sV + c1 * 8 - lane * 8;
  for (int kt = 0; kt < S_ / 64; ++kt) {
    const int gk = kt * 64;
    gload16(kb + (long)(gk + r0) * DKH + sl0 * 8, dst0);
    gload16(kb + (long)(gk + r1) * DKH + sl1 * 8, dst1);
    gload16(vb + (long)r0 * S_ + gk + sl0 * 8, dstV0);
    gload16(vb + (long)r1 * S_ + gk + sl1 * 8, dstV1);
    __syncthreads();
    f32x4 sacc[4] = {};
    #pragma unroll
    for (int nc = 0; nc < 4; ++nc) {
      const int kr = nc * 16 + lc;
      bf16x8 k0 = *(const bf16x8*)((char*)sK + kr * 128 + (((0 + lg) ^ (kr & 7)) << 4));
      bf16x8 k1 = *(const bf16x8*)((char*)sK + kr * 128 + (((4 + lg) ^ (kr & 7)) << 4));
      sacc[nc] = __builtin_amdgcn_mfma_f32_16x16x32_bf16(k0, qf0, sacc[nc], 0, 0, 0);
      sacc[nc] = __builtin_amdgcn_mfma_f32_16x16x32_bf16(k1, qf1, sacc[nc], 0, 0, 0);
    }
    float pm = sacc[0][0];
    #pragma unroll
    for (int nc = 0; nc < 4; ++nc)
      #pragma unroll
      for (int r = 0; r < 4; ++r) pm = fmaxf(pm, sacc[nc][r]);
    pm = fmaxf(pm, __shfl_xor(pm, 16));
    pm = fmaxf(pm, __shfl_xor(pm, 32));
    const float mnew = fmaxf(mrun, pm);
    const float fac = __expf(mrun - mnew);
    float ps = 0.f;
    #pragma unroll
    for (int nc = 0; nc < 4; ++nc)
      #pragma unroll
      for (int r = 0; r < 4; ++r) {
        const float p = __expf(sacc[nc][r] - mnew);
        sacc[nc][r] = p;
        ps += p;
      }
    ps += __shfl_xor(ps, 16);
    ps += __shfl_xor(ps, 32);
    lrun = lrun * fac + ps;
    mrun = mnew;
    #pragma unroll
    for (int nc = 0; nc < 4; ++nc)
      #pragma unroll
      for (int rp = 0; rp < 2; ++rp) {
        bf16x2 t;
        t[0] = (bf16)sacc[nc][rp * 2 + 0];
        t[1] = (bf16)sacc[nc][rp * 2 + 1];
        *(bf16x2*)((char*)sPw + lc * 128 + ((nc * 32 + lg * 8 + rp * 4) ^ swzP)) = t;
      }
    asm volatile("s_waitcnt lgkmcnt(0)" ::: "memory");
    __builtin_amdgcn_sched_barrier(0);
    float fr[4];
    #pragma unroll
    for (int r = 0; r < 4; ++r) fr[r] = __shfl(fac, lg * 4 + r);
    #pragma unroll
    for (int nc = 0; nc < 4; ++nc)
      #pragma unroll
      for (int r = 0; r < 4; ++r) oacc[nc][r] *= fr[r];
    #pragma unroll
    for (int m = 0; m < 2; ++m) {
      const bf16x8 pf = *(const bf16x8*)((char*)sPw + lc * 128 + ((m * 64 + lg * 16) ^ swzP));
      #pragma unroll
      for (int nc = 0; nc < 4; ++nc) {
        const int vr = nc * 16 + lc;
        bf16x8 vf = *(const bf16x8*)((char*)sV + vr * 128 + (((m * 4 + lg) ^ (vr & 7)) << 4));
        oacc[nc] = __builtin_amdgcn_mfma_f32_16x16x32_bf16(pf, vf, oacc[nc], 0, 0, 0);
      }
    }
    __syncthreads();
  }
  const int b = bh >> 4, h = bh & 15;
  const float linv = 1.f / lrun;
  #pragma unroll
  for (int r = 0; r < 4; ++r) {
    const float inv = __shfl(linv, lg * 4 + r);
    const int s = qt * 64 + wv * 16 + lg * 4 + r;
    const long obase = (((long)b * S_ + s) * H_ + h) * DKH;
    #pragma unroll
    for (int nc = 0; nc < 4; ++nc)
      og[obase + nc * 16 + lc] = (bf16)(oacc[nc][r] * inv);
  }
}

// ---------------- fused residual add + LayerNorm (bf16 residual stream) ----------------
template<int TWO>
__global__ __launch_bounds__(256)
void k_addln(const bf16* __restrict__ hin, const bf16* __restrict__ dlt,
             const bf16* __restrict__ p0, const bf16* __restrict__ p1,
             const float* __restrict__ gb,
             const float* __restrict__ sc, const float* __restrict__ bi,
             bf16* __restrict__ hbout) {
  const int row = blockIdx.x, t = threadIdx.x;
  const long off = (long)row * D_ + t * 4;
  bf16x4 hv = *(const bf16x4*)(hin + off);
  f32x4 x;
  if constexpr (TWO) {
    bf16x4 a = *(const bf16x4*)(p0 + off);
    bf16x4 b = *(const bf16x4*)(p1 + off);
    f32x4 g = *(const f32x4*)(gb + t * 4);
    #pragma unroll
    for (int j = 0; j < 4; ++j) x[j] = (float)hv[j] + (float)a[j] + (float)b[j] + g[j];
  } else {
    bf16x4 dv = *(const bf16x4*)(dlt + off);
    #pragma unroll
    for (int j = 0; j < 4; ++j) x[j] = (float)hv[j] + (float)dv[j];
  }
  float s = 0.f, ss = 0.f;
  #pragma unroll
  for (int j = 0; j < 4; ++j) { s += x[j]; ss += x[j] * x[j]; }
  #pragma unroll
  for (int m = 1; m < 64; m <<= 1) { s += __shfl_xor(s, m); ss += __shfl_xor(ss, m); }
  __shared__ float red[8];
  const int w = t >> 6, ln = t & 63;
  if (ln == 0) { red[w] = s; red[4 + w] = ss; }
  __syncthreads();
  s = red[0] + red[1] + red[2] + red[3];
  ss = red[4] + red[5] + red[6] + red[7];
  const float mu = s * (1.f / D_);
  const float rstd = rsqrtf(ss * (1.f / D_) - mu * mu + 1e-5f);
  f32x4 scv = *(const f32x4*)(sc + t * 4);
  f32x4 biv = *(const f32x4*)(bi + t * 4);
  bf16x4 yb;
  #pragma unroll
  for (int j = 0; j < 4; ++j) yb[j] = (bf16)((x[j] - mu) * rstd * scv[j] + biv[j]);
  *(bf16x4*)(hbout + off) = yb;
}

// ---------------- mean-pool (2-stage) + FC ----------------
__global__ __launch_bounds__(256)
void k_pool1(const bf16* __restrict__ h, float* __restrict__ part) {
  const int i = blockIdx.x * 256 + threadIdx.x;
  const int b = i >> 10, d = i & 1023;
  const int s0 = blockIdx.y * 128;
  float s = 0.f;
  for (int t = 0; t < 128; ++t) s += (float)h[((long)b * S_ + s0 + t) * D_ + d];
  part[(long)blockIdx.y * NTOK + i] = s;
}

__global__ __launch_bounds__(256)
void k_pool2(const float* __restrict__ part, float* __restrict__ pooled) {
  const int i = blockIdx.x * 256 + threadIdx.x;
  float s = 0.f;
  #pragma unroll
  for (int j = 0; j < 8; ++j) s += part[(long)j * NTOK + i];
  pooled[i] = s * (1.f / S_);
}

__global__ __launch_bounds__(64)
void k_fc(const float* __restrict__ pooled, const float* __restrict__ fw,
          const float* __restrict__ fb, float* __restrict__ out) {
  const int b = blockIdx.x / 10, c = blockIdx.x % 10;
  const int lane = threadIdx.x;
  float s = 0.f;
  for (int d = lane; d < D_; d += 64) s += pooled[b * D_ + d] * fw[d * 10 + c];
  #pragma unroll
  for (int m = 1; m < 64; m <<= 1) s += __shfl_xor(s, m);
  if (lane == 0) out[b * 10 + c] = s + fb[c];
}

// ---------------- host launcher ----------------
extern "C" void kernel_launch(void* const* d_in, const int* in_sizes, int n_in,
                              void* d_out, int out_size, void* d_ws, size_t ws_size,
                              hipStream_t stream) {
  const float* x     = (const float*)d_in[0];
  const float* emb_w = (const float*)d_in[1];
  const float* emb_b = (const float*)d_in[2];
  const float* Wq    = (const float*)d_in[3];
  const float* bq    = (const float*)d_in[4];
  const float* Wk    = (const float*)d_in[5];
  const float* bk    = (const float*)d_in[6];
  const float* Wv    = (const float*)d_in[7];
  const float* bv    = (const float*)d_in[8];
  const float* Wo    = (const float*)d_in[9];
  const float* bo    = (const float*)d_in[10];
  const float* W1    = (const float*)d_in[11];
  const float* b1    = (const float*)d_in[12];
  const float* W2    = (const float*)d_in[13];
  const float* b2    = (const float*)d_in[14];
  const float* ln1s  = (const float*)d_in[15];
  const float* ln1b  = (const float*)d_in[16];
  const float* ln2s  = (const float*)d_in[17];
  const float* ln2b  = (const float*)d_in[18];
  const float* fcw   = (const float*)d_in[19];
  const float* fcb   = (const float*)d_in[20];

  char* w = (char*)d_ws;
  size_t off = 0;
  auto alloc = [&](size_t bytes) -> char* {
    char* p = w + off;
    off += (bytes + 255) & ~(size_t)255;
    return p;
  };
  bf16*  x_bf  = (bf16*) alloc((size_t)NTOK * IND * 2);
  bf16*  embT  = (bf16*) alloc((size_t)D_ * IND * 2);
  bf16*  qkvT  = (bf16*) alloc((size_t)L_ * 3 * D_ * D_ * 2);
  bf16*  woT   = (bf16*) alloc((size_t)L_ * D_ * D_ * 2);
  bf16*  w1T   = (bf16*) alloc((size_t)L_ * FF * D_ * 2);
  bf16*  w2T   = (bf16*) alloc((size_t)L_ * D_ * FF * 2);
  float* qkvB  = (float*)alloc((size_t)L_ * 3 * D_ * 4);
  float* pe    = (float*)alloc((size_t)B_ * D_ * 4);
  bf16*  h_b   = (bf16*) alloc((size_t)NTOK * D_ * 2);
  bf16*  delta = (bf16*) alloc((size_t)NTOK * D_ * 2);
  float* pooled= (float*)alloc((size_t)B_ * D_ * 4);
  float* part  = (float*)alloc((size_t)8 * NTOK * 4);
  bf16*  scratch = (bf16*)alloc((size_t)NTOK * FF * 2);
  bf16* qb  = scratch;
  bf16* kb  = scratch + (size_t)NTOK * D_;
  bf16* vTb = scratch + (size_t)2 * NTOK * D_;
  bf16* ob  = scratch + (size_t)3 * NTOK * D_;
  bf16* ffn1 = scratch;
  bf16* p0 = (bf16*)alloc((size_t)NTOK * D_ * 2);
  bf16* p1 = (bf16*)alloc((size_t)NTOK * D_ * 2);
  const bool canSplit = (off <= ws_size);
  (void)in_sizes; (void)n_in; (void)out_size;

  k_f2b<<<dim3(NTOK * IND / 1024), dim3(256), 0, stream>>>(x, x_bf);
  k_trans<<<dim3(D_ / 64, IND / 64, 1), dim3(256), 0, stream>>>(emb_w, embT, IND, D_, 0, 0);
  k_trans<<<dim3(D_ / 64, D_ / 64, L_), dim3(256), 0, stream>>>(Wq, qkvT,               D_, D_, (long)D_ * D_, (long)3 * D_ * D_);
  k_trans<<<dim3(D_ / 64, D_ / 64, L_), dim3(256), 0, stream>>>(Wk, qkvT + D_ * D_,     D_, D_, (long)D_ * D_, (long)3 * D_ * D_);
  k_trans<<<dim3(D_ / 64, D_ / 64, L_), dim3(256), 0, stream>>>(Wv, qkvT + 2 * D_ * D_, D_, D_, (long)D_ * D_, (long)3 * D_ * D_);
  k_trans<<<dim3(D_ / 64, D_ / 64, L_), dim3(256), 0, stream>>>(Wo, woT, D_, D_, (long)D_ * D_, (long)D_ * D_);
  k_trans<<<dim3(FF / 64, D_ / 64, L_), dim3(256), 0, stream>>>(W1, w1T, D_, FF, (long)D_ * FF, (long)FF * D_);
  k_trans<<<dim3(D_ / 64, FF / 64, L_), dim3(256), 0, stream>>>(W2, w2T, FF, D_, (long)FF * D_, (long)D_ * FF);
  k_pe<<<dim3(B_ * D_ / 256), dim3(256), 0, stream>>>(pe);
  k_packb<<<dim3(L_ * 3 * D_ / 256), dim3(256), 0, stream>>>(bq, bk, bv, qkvB);

  k_gemm<3><<<dim3(D_ / 128, NTOK / 128), dim3(256), 0, stream>>>(
      x_bf, embT, emb_b, nullptr, h_b, pe, NTOK, D_, IND);

  for (int l = 0; l < L_; ++l) {
    k_gemm256<2, 0><<<dim3(3 * D_ / 256, NTOK / 256), dim3(512), 0, stream>>>(
        h_b, qkvT + (size_t)l * 3 * D_ * D_, qkvB + l * 3 * D_,
        qb, vTb, nullptr, nullptr, NTOK, 3 * D_, D_);
    k_flash<<<dim3(S_ / 64, B_ * H_), dim3(256), 0, stream>>>(qb, kb, vTb, ob);
    if (canSplit) {
      k_gemm256<0, 1><<<dim3(D_ / 256, NTOK / 256, 2), dim3(512), 0, stream>>>(
          ob, woT + (size_t)l * D_ * D_, nullptr,
          nullptr, nullptr, p0, p1, NTOK, D_, D_);
      k_addln<1><<<dim3(NTOK), dim3(256), 0, stream>>>(
          h_b, nullptr, p0, p1, bo + l * D_, ln1s + l * D_, ln1b + l * D_, h_b);
    } else {
      k_gemm256<0, 0><<<dim3(D_ / 256, NTOK / 256), dim3(512), 0, stream>>>(
          ob, woT + (size_t)l * D_ * D_, bo + l * D_,
          delta, nullptr, nullptr, nullptr, NTOK, D_, D_);
      k_addln<0><<<dim3(NTOK), dim3(256), 0, stream>>>(
          h_b, delta, nullptr, nullptr, nullptr, ln1s + l * D_, ln1b + l * D_, h_b);
    }
    // FFN1 on the ring-3 128^2 kernel (A/B vs k_gemm256 this round)
    k_g128<1><<<dim3(FF / 128, NTOK / 128), dim3(256), 0, stream>>>(
        h_b, w1T + (size_t)l * FF * D_, b1 + l * FF,
        ffn1, NTOK, FF, D_);
    if (canSplit) {
      k_gemm256<0, 1><<<dim3(D_ / 256, NTOK / 256, 2), dim3(512), 0, stream>>>(
          ffn1, w2T + (size_t)l * D_ * FF, nullptr,
          nullptr, nullptr, p0, p1, NTOK, D_, FF);
      k_addln<1><<<dim3(NTOK), dim3(256), 0, stream>>>(
          h_b, nullptr, p0, p1, b2 + l * D_, ln2s + l * D_, ln2b + l * D_, h_b);
    } else {
      k_gemm256<0, 0><<<dim3(D_ / 256, NTOK / 256), dim3(512), 0, stream>>>(
          ffn1, w2T + (size_t)l * D_ * FF, b2 + l * D_,
          delta, nullptr, nullptr, nullptr, NTOK, D_, FF);
      k_addln<0><<<dim3(NTOK), dim3(256), 0, stream>>>(
          h_b, delta, nullptr, nullptr, nullptr, ln2s + l * D_, ln2b + l * D_, h_b);
    }
  }

  k_pool1<<<dim3(NTOK / 256, 8), dim3(256), 0, stream>>>(h_b, part);
  k_pool2<<<dim3(NTOK / 256), dim3(256), 0, stream>>>(part, pooled);
  k_fc<<<dim3(B_ * 10), dim3(64), 0, stream>>>(pooled, fcw, fcb, (float*)d_out);
}

// Round 15
// 2185.038 us; speedup vs baseline: 1.1382x; 1.1382x over previous
//
#include <hip/hip_runtime.h>
#include <stdint.h>

#define B_   8
#define S_   1024
#define IND  256
#define D_   1024
#define H_   16
#define DKH  64
#define L_   6
#define FF   4096
#define NTOK (B_*S_)

typedef __bf16 bf16;
typedef __attribute__((ext_vector_type(4))) float  f32x4;
typedef __attribute__((ext_vector_type(8))) __bf16 bf16x8;
typedef __attribute__((ext_vector_type(4))) __bf16 bf16x4;
typedef __attribute__((ext_vector_type(2))) __bf16 bf16x2;

#define AS1 __attribute__((address_space(1)))
#define AS3 __attribute__((address_space(3)))

__device__ __forceinline__ void gload16(const void* g, void* l) {
  __builtin_amdgcn_global_load_lds((AS1 void*)(const_cast<void*>(g)), (AS3 void*)l, 16, 0, 0);
}

// ---------------- weight transpose+convert: in [K][N] f32 -> out [N][K] bf16 ----------------
__global__ __launch_bounds__(256)
void k_trans(const float* __restrict__ in, bf16* __restrict__ out,
             int K, int N, long inStride, long outStride) {
  __shared__ float t[64][65];
  const float* inp = in + (long)blockIdx.z * inStride;
  bf16* outp = out + (long)blockIdx.z * outStride;
  const int n0 = blockIdx.x * 64, k0 = blockIdx.y * 64;
  const int r = threadIdx.x >> 4;
  const int c4 = (threadIdx.x & 15) * 4;
  #pragma unroll
  for (int j = 0; j < 64; j += 16) {
    f32x4 v = *(const f32x4*)(inp + (long)(k0 + r + j) * N + n0 + c4);
    #pragma unroll
    for (int i = 0; i < 4; ++i) t[r + j][c4 + i] = v[i];
  }
  __syncthreads();
  #pragma unroll
  for (int j = 0; j < 64; j += 16) {
    const int n = r + j;
    bf16x4 o;
    #pragma unroll
    for (int i = 0; i < 4; ++i) o[i] = (bf16)t[c4 + i][n];
    *(bf16x4*)(outp + (long)(n0 + n) * K + k0 + c4) = o;
  }
}

// ---------------- fp32 -> bf16 elementwise ----------------
__global__ __launch_bounds__(256)
void k_f2b(const float* __restrict__ in, bf16* __restrict__ out) {
  const long i = ((long)blockIdx.x * 256 + threadIdx.x) * 4;
  f32x4 v = *(const f32x4*)(in + i);
  bf16x4 o;
  #pragma unroll
  for (int j = 0; j < 4; ++j) o[j] = (bf16)v[j];
  *(bf16x4*)(out + i) = o;
}

// ---------------- positional encoding rows ----------------
__global__ __launch_bounds__(256)
void k_pe(float* __restrict__ pe) {
  const int i = blockIdx.x * 256 + threadIdx.x;
  const int b = i >> 10, d = i & 1023;
  const float k2 = (float)(d & ~1);
  const float dv = __expf(k2 * (-9.210340371976184f / (float)D_));
  const float a = (float)b * dv;
  pe[i] = (d & 1) ? cosf(a) : sinf(a);
}

// ---------------- pack per-layer qkv bias [L][3072] ----------------
__global__ __launch_bounds__(256)
void k_packb(const float* __restrict__ bq, const float* __restrict__ bk,
             const float* __restrict__ bv, float* __restrict__ out) {
  const int i = blockIdx.x * 256 + threadIdx.x;
  const int l = i / 3072, j = i % 3072;
  const float* src = (j < 1024) ? bq : ((j < 2048) ? bk : bv);
  out[i] = src[l * 1024 + (j & 1023)];
}

// ---------------- 128^2 GEMM — embedding (EPI 3: +pe, bf16 out) ----------------
template<int EPI>
__global__ __launch_bounds__(256)
void k_gemm(const bf16* __restrict__ A, const bf16* __restrict__ Bt,
            const float* __restrict__ bias,
            void* __restrict__ out0, void* __restrict__ out1,
            const float* __restrict__ pe,
            int M, int N, int K) {
  __shared__ __align__(16) bf16 sA[128 * 32];
  __shared__ __align__(16) bf16 sB[128 * 32];
  const int tid = threadIdx.x;
  const int lane = tid & 63, wv = tid >> 6;
  const int bx = blockIdx.x, by = blockIdx.y;
  const int wm = wv >> 1, wn = wv & 1;
  const int lg = lane >> 4, lc = lane & 15;
  const long arow0 = (long)by * 128;
  const long brow0 = (long)bx * 128;
  const int c0 = (wv * 2 + 0) * 64 + lane;
  const int c1 = (wv * 2 + 1) * 64 + lane;
  const int r0 = c0 >> 2, s0 = c0 & 3;
  const int r1 = c1 >> 2, s1 = c1 & 3;
  bf16* ldsA0 = sA + (wv * 2 + 0) * 512;
  bf16* ldsA1 = sA + (wv * 2 + 1) * 512;
  bf16* ldsB0 = sB + (wv * 2 + 0) * 512;
  bf16* ldsB1 = sB + (wv * 2 + 1) * 512;
  const bf16* Ab = A + arow0 * K;
  const bf16* Bb = Bt + brow0 * K;
  f32x4 acc[4][4] = {};
  const int kT = K >> 5;
  for (int kt = 0; kt < kT; ++kt) {
    const int k0 = kt << 5;
    gload16(Ab + (long)r0 * K + k0 + s0 * 8, ldsA0);
    gload16(Ab + (long)r1 * K + k0 + s1 * 8, ldsA1);
    gload16(Bb + (long)r0 * K + k0 + s0 * 8, ldsB0);
    gload16(Bb + (long)r1 * K + k0 + s1 * 8, ldsB1);
    __syncthreads();
    bf16x8 af[4], bfr[4];
    #pragma unroll
    for (int mr = 0; mr < 4; ++mr)
      af[mr] = *(const bf16x8*)(sA + (wm * 64 + mr * 16 + lc) * 32 + lg * 8);
    #pragma unroll
    for (int nc = 0; nc < 4; ++nc)
      bfr[nc] = *(const bf16x8*)(sB + (wn * 64 + nc * 16 + lc) * 32 + lg * 8);
    #pragma unroll
    for (int mr = 0; mr < 4; ++mr)
      #pragma unroll
      for (int nc = 0; nc < 4; ++nc)
        acc[mr][nc] = __builtin_amdgcn_mfma_f32_16x16x32_bf16(af[mr], bfr[nc], acc[mr][nc], 0, 0, 0);
    __syncthreads();
  }
  #pragma unroll
  for (int mr = 0; mr < 4; ++mr) {
    const int row0 = by * 128 + wm * 64 + mr * 16 + lg * 4;
    #pragma unroll
    for (int nc = 0; nc < 4; ++nc) {
      const int col = bx * 128 + wn * 64 + nc * 16 + lc;
      const float bvv = bias[col];
      #pragma unroll
      for (int r = 0; r < 4; ++r) {
        float v = acc[mr][nc][r] + bvv;
        const long rr = row0 + r;
        if constexpr (EPI == 0) {
          ((bf16*)out0)[rr * N + col] = (bf16)v;
        } else {
          const long bb = rr >> 10;
          v += pe[bb * D_ + col];
          ((bf16*)out1)[rr * N + col] = (bf16)v;
        }
      }
    }
  }
}

// ---------------- 256^2 8-phase GEMM (R5 schedule — banked best) ----------------
// EPI 1: relu bf16; 2: qkv scatter (q*0.125->[B,H,S,DK], k->[B,H,S,DK], v->VT [B,H,DK,S]).
// SPLIT=1: blockIdx.z picks K-half; both halves write BF16 partials (bias added in addln).
template<int EPI, int SPLIT>
__global__ __launch_bounds__(512, 2)
void k_gemm256(const bf16* __restrict__ A, const bf16* __restrict__ Bt,
               const float* __restrict__ bias,
               void* __restrict__ out0, void* __restrict__ out1,
               bf16* __restrict__ pout0, bf16* __restrict__ pout1,
               int M, int N, int K) {
  __shared__ __align__(16) bf16 lds[65536];
  const int tid = threadIdx.x;
  const int lane = tid & 63, wv = tid >> 6;
  const int wm = wv >> 2, wn = wv & 3;
  const int lg = lane >> 4, lc = lane & 15;
  const int gx = gridDim.x;
  const int nwg = gx * gridDim.y;
  int bid = blockIdx.x + blockIdx.y * gx;
  const int cpx = nwg >> 3;
  bid = (bid & 7) * cpx + (bid >> 3);
  const int bxs = bid % gx, bys = bid / gx;
  const int tileRow = bys * 256, tileCol = bxs * 256;
  const int kPart = SPLIT ? (K >> 1) : K;
  const long kOff = SPLIT ? (long)blockIdx.z * kPart : 0;
  const bf16* Abase = A + (long)tileRow * K + kOff;
  const bf16* Bbase = Bt + (long)tileCol * K + kOff;
  const long laneOff = (long)lc * K + lg * 8;
  f32x4 acc[8][4] = {};
  const int NT = kPart >> 6;
  const int NI = NT >> 1;

  auto stA = [&](int t, int h, int bb) {
    const int rg = h * 16 + wv * 2;
    const int mb = rg >> 1;
    const bf16* s = Abase + (long)(mb * 16) * K + t * 64 + laneOff;
    bf16* d = lds + bb * 32768 + rg * 512;
    gload16(s, d);
    gload16(s + 32, d + 512);
  };
  auto stB = [&](int t, int h, int bb) {
    const int rg = h * 16 + wv * 2;
    const int mb = rg >> 1;
    const bf16* s = Bbase + (long)(mb * 16) * K + t * 64 + laneOff;
    bf16* d = lds + bb * 32768 + 16384 + rg * 512;
    gload16(s, d);
    gload16(s + 32, d + 512);
  };

  bf16x8 aF[8];
  bf16x8 bF0[4], bF1[4];

#define LDA(BB, MH) do { _Pragma("unroll") for (int m = 0; m < 4; ++m) \
    _Pragma("unroll") for (int kk = 0; kk < 2; ++kk) \
      aF[m*2+kk] = *(const bf16x8*)(lds + (BB)*32768 + ((wm*8 + (MH)*4 + m)*2 + kk)*512 + lane*8); \
  } while(0)
#define LDB(BB, NH, DST) do { _Pragma("unroll") for (int n = 0; n < 2; ++n) \
    _Pragma("unroll") for (int kk = 0; kk < 2; ++kk) \
      DST[n*2+kk] = *(const bf16x8*)(lds + (BB)*32768 + 16384 + ((wn*4 + (NH)*2 + n)*2 + kk)*512 + lane*8); \
  } while(0)
#define MMA(MH, NH, BSRC) do { \
    __builtin_amdgcn_s_setprio(1); \
    _Pragma("unroll") for (int m = 0; m < 4; ++m) \
      _Pragma("unroll") for (int n = 0; n < 2; ++n) { \
        acc[(MH)*4+m][(NH)*2+n] = __builtin_amdgcn_mfma_f32_16x16x32_bf16(aF[m*2+0], BSRC[n*2+0], acc[(MH)*4+m][(NH)*2+n], 0, 0, 0); \
        acc[(MH)*4+m][(NH)*2+n] = __builtin_amdgcn_mfma_f32_16x16x32_bf16(aF[m*2+1], BSRC[n*2+1], acc[(MH)*4+m][(NH)*2+n], 0, 0, 0); \
      } \
    __builtin_amdgcn_s_setprio(0); \
  } while(0)
#define VM8 asm volatile("s_waitcnt vmcnt(8)" ::: "memory")
#define VM0 asm volatile("s_waitcnt vmcnt(0)" ::: "memory")
#define BAR __builtin_amdgcn_s_barrier()

  stA(0, 0, 0); stB(0, 0, 0); stA(0, 1, 0); stB(0, 1, 0);
  stA(1, 0, 1); stB(1, 0, 1); stA(1, 1, 1); stB(1, 1, 1);

  for (int i = 0; i < NI - 1; ++i) {
    const int t2 = 2 * i + 2, t3 = 2 * i + 3;
    VM8; BAR; LDA(0, 0); LDB(0, 0, bF0);   MMA(0, 0, bF0);
         BAR; LDB(0, 1, bF1); stA(t2, 0, 0);              MMA(0, 1, bF1);
         BAR; LDA(0, 1);      stB(t2, 0, 0);              MMA(1, 0, bF0);
         BAR; stA(t2, 1, 0);  stB(t2, 1, 0);              MMA(1, 1, bF1);
    VM8; BAR; LDA(1, 0); LDB(1, 0, bF0);   MMA(0, 0, bF0);
         BAR; LDB(1, 1, bF1); stA(t3, 0, 1);              MMA(0, 1, bF1);
         BAR; LDA(1, 1);      stB(t3, 0, 1);              MMA(1, 0, bF0);
         BAR; stA(t3, 1, 1);  stB(t3, 1, 1);              MMA(1, 1, bF1);
  }
  {
    VM8; BAR; LDA(0, 0); LDB(0, 0, bF0); MMA(0, 0, bF0);
         BAR; LDB(0, 1, bF1);            MMA(0, 1, bF1);
         BAR; LDA(0, 1);                 MMA(1, 0, bF0);
         BAR;                            MMA(1, 1, bF1);
    VM0; BAR; LDA(1, 0); LDB(1, 0, bF0); MMA(0, 0, bF0);
         BAR; LDB(1, 1, bF1);            MMA(0, 1, bF1);
         BAR; LDA(1, 1);                 MMA(1, 0, bF0);
         BAR;                            MMA(1, 1, bF1);
  }
#undef LDA
#undef LDB
#undef MMA
#undef VM8
#undef VM0
#undef BAR

  #pragma unroll
  for (int mr = 0; mr < 8; ++mr) {
    const int row0 = tileRow + wm * 128 + mr * 16 + lg * 4;
    #pragma unroll
    for (int nr = 0; nr < 4; ++nr) {
      const int col = tileCol + wn * 64 + nr * 16 + lc;
      if constexpr (SPLIT) {
        bf16* po = blockIdx.z ? pout1 : pout0;
        #pragma unroll
        for (int r = 0; r < 4; ++r)
          po[(long)(row0 + r) * N + col] = (bf16)acc[mr][nr][r];
      } else if constexpr (EPI == 2) {
        const float bvv = bias[col];
        const int which = col >> 10;
        const int hh = (col & 1023) >> 6;
        const int dk = col & 63;
        const long bb = row0 >> 10;
        const int sr = row0 & 1023;
        if (which == 2) {
          bf16x4 pk;
          #pragma unroll
          for (int r = 0; r < 4; ++r) pk[r] = (bf16)(acc[mr][nr][r] + bvv);
          *(bf16x4*)((bf16*)out1 + ((bb * H_ + hh) * (long)DKH + dk) * S_ + sr) = pk;
        } else {
          #pragma unroll
          for (int r = 0; r < 4; ++r) {
            float v = acc[mr][nr][r] + bvv;
            if (which == 0) v *= 0.125f;
            ((bf16*)out0)[(long)which * NTOK * D_ + ((bb * H_ + hh) * (long)S_ + sr + r) * DKH + dk] = (bf16)v;
          }
        }
      } else {
        const float bvv = bias[col];
        #pragma unroll
        for (int r = 0; r < 4; ++r) {
          float v = acc[mr][nr][r] + bvv;
          const long rr = row0 + r;
          if constexpr (EPI == 1) v = fmaxf(v, 0.f);
          ((bf16*)out0)[rr * N + col] = (bf16)v;
        }
      }
    }
  }
}

// ---------------- flash attention (XCD-swizzled) ----------------
__global__ __launch_bounds__(256)
void k_flash(const bf16* __restrict__ qg, const bf16* __restrict__ kgl,
             const bf16* __restrict__ vtg, bf16* __restrict__ og) {
  __shared__ __align__(16) bf16 sK[64 * 64];
  __shared__ __align__(16) bf16 sV[64 * 64];
  __shared__ __align__(16) bf16 sP[4 * 16 * 64];
  const int tid = threadIdx.x, lane = tid & 63, wv = tid >> 6;
  const int lg = lane >> 4, lc = lane & 15;
  int bid = blockIdx.x + blockIdx.y * 16;
  bid = (bid & 7) * 256 + (bid >> 3);
  const int qt = bid & 15, bh = bid >> 4;
  const long base = (long)bh * S_ * DKH;
  const bf16* qb = qg + base;
  const bf16* kb = kgl + base;
  const bf16* vb = vtg + base;
  const int qrow = qt * 64 + wv * 16 + lc;
  const bf16x8 qf0 = *(const bf16x8*)(qb + (long)qrow * DKH + lg * 8);
  const bf16x8 qf1 = *(const bf16x8*)(qb + (long)qrow * DKH + 32 + lg * 8);
  float mrun = -3e38f, lrun = 0.f;
  f32x4 oacc[4] = {};
  bf16* sPw = sP + wv * (16 * 64);
  const int swzP = (lc & 7) << 4;
  const int c0 = wv * 128 + lane, c1 = c0 + 64;
  const int r0 = c0 >> 3, sl0 = (c0 & 7) ^ (r0 & 7);
  const int r1 = c1 >> 3, sl1 = (c1 & 7) ^ (r1 & 7);
  bf16* dst0 = sK + c0 * 8 - lane * 8;
  bf16* dst1 = sK + c1 * 8 - lane * 8;
  bf16* dstV0 = sV + c0 * 8 - lane * 8;
  bf16* dstV1 = sV + c1 * 8 - lane * 8;
  for (int kt = 0; kt < S_ / 64; ++kt) {
    const int gk = kt * 64;
    gload16(kb + (long)(gk + r0) * DKH + sl0 * 8, dst0);
    gload16(kb + (long)(gk + r1) * DKH + sl1 * 8, dst1);
    gload16(vb + (long)r0 * S_ + gk + sl0 * 8, dstV0);
    gload16(vb + (long)r1 * S_ + gk + sl1 * 8, dstV1);
    __syncthreads();
    f32x4 sacc[4] = {};
    #pragma unroll
    for (int nc = 0; nc < 4; ++nc) {
      const int kr = nc * 16 + lc;
      bf16x8 k0 = *(const bf16x8*)((char*)sK + kr * 128 + (((0 + lg) ^ (kr & 7)) << 4));
      bf16x8 k1 = *(const bf16x8*)((char*)sK + kr * 128 + (((4 + lg) ^ (kr & 7)) << 4));
      sacc[nc] = __builtin_amdgcn_mfma_f32_16x16x32_bf16(k0, qf0, sacc[nc], 0, 0, 0);
      sacc[nc] = __builtin_amdgcn_mfma_f32_16x16x32_bf16(k1, qf1, sacc[nc], 0, 0, 0);
    }
    float pm = sacc[0][0];
    #pragma unroll
    for (int nc = 0; nc < 4; ++nc)
      #pragma unroll
      for (int r = 0; r < 4; ++r) pm = fmaxf(pm, sacc[nc][r]);
    pm = fmaxf(pm, __shfl_xor(pm, 16));
    pm = fmaxf(pm, __shfl_xor(pm, 32));
    const float mnew = fmaxf(mrun, pm);
    const float fac = __expf(mrun - mnew);
    float ps = 0.f;
    #pragma unroll
    for (int nc = 0; nc < 4; ++nc)
      #pragma unroll
      for (int r = 0; r < 4; ++r) {
        const float p = __expf(sacc[nc][r] - mnew);
        sacc[nc][r] = p;
        ps += p;
      }
    ps += __shfl_xor(ps, 16);
    ps += __shfl_xor(ps, 32);
    lrun = lrun * fac + ps;
    mrun = mnew;
    #pragma unroll
    for (int nc = 0; nc < 4; ++nc)
      #pragma unroll
      for (int rp = 0; rp < 2; ++rp) {
        bf16x2 t;
        t[0] = (bf16)sacc[nc][rp * 2 + 0];
        t[1] = (bf16)sacc[nc][rp * 2 + 1];
        *(bf16x2*)((char*)sPw + lc * 128 + ((nc * 32 + lg * 8 + rp * 4) ^ swzP)) = t;
      }
    asm volatile("s_waitcnt lgkmcnt(0)" ::: "memory");
    __builtin_amdgcn_sched_barrier(0);
    float fr[4];
    #pragma unroll
    for (int r = 0; r < 4; ++r) fr[r] = __shfl(fac, lg * 4 + r);
    #pragma unroll
    for (int nc = 0; nc < 4; ++nc)
      #pragma unroll
      for (int r = 0; r < 4; ++r) oacc[nc][r] *= fr[r];
    #pragma unroll
    for (int m = 0; m < 2; ++m) {
      const bf16x8 pf = *(const bf16x8*)((char*)sPw + lc * 128 + ((m * 64 + lg * 16) ^ swzP));
      #pragma unroll
      for (int nc = 0; nc < 4; ++nc) {
        const int vr = nc * 16 + lc;
        bf16x8 vf = *(const bf16x8*)((char*)sV + vr * 128 + (((m * 4 + lg) ^ (vr & 7)) << 4));
        oacc[nc] = __builtin_amdgcn_mfma_f32_16x16x32_bf16(pf, vf, oacc[nc], 0, 0, 0);
      }
    }
    __syncthreads();
  }
  const int b = bh >> 4, h = bh & 15;
  const float linv = 1.f / lrun;
  #pragma unroll
  for (int r = 0; r < 4; ++r) {
    const float inv = __shfl(linv, lg * 4 + r);
    const int s = qt * 64 + wv * 16 + lg * 4 + r;
    const long obase = (((long)b * S_ + s) * H_ + h) * DKH;
    #pragma unroll
    for (int nc = 0; nc < 4; ++nc)
      og[obase + nc * 16 + lc] = (bf16)(oacc[nc][r] * inv);
  }
}

// ---------------- fused residual add + LayerNorm (bf16 residual stream) ----------------
template<int TWO>
__global__ __launch_bounds__(256)
void k_addln(const bf16* __restrict__ hin, const bf16* __restrict__ dlt,
             const bf16* __restrict__ p0, const bf16* __restrict__ p1,
             const float* __restrict__ gb,
             const float* __restrict__ sc, const float* __restrict__ bi,
             bf16* __restrict__ hbout) {
  const int row = blockIdx.x, t = threadIdx.x;
  const long off = (long)row * D_ + t * 4;
  bf16x4 hv = *(const bf16x4*)(hin + off);
  f32x4 x;
  if constexpr (TWO) {
    bf16x4 a = *(const bf16x4*)(p0 + off);
    bf16x4 b = *(const bf16x4*)(p1 + off);
    f32x4 g = *(const f32x4*)(gb + t * 4);
    #pragma unroll
    for (int j = 0; j < 4; ++j) x[j] = (float)hv[j] + (float)a[j] + (float)b[j] + g[j];
  } else {
    bf16x4 dv = *(const bf16x4*)(dlt + off);
    #pragma unroll
    for (int j = 0; j < 4; ++j) x[j] = (float)hv[j] + (float)dv[j];
  }
  float s = 0.f, ss = 0.f;
  #pragma unroll
  for (int j = 0; j < 4; ++j) { s += x[j]; ss += x[j] * x[j]; }
  #pragma unroll
  for (int m = 1; m < 64; m <<= 1) { s += __shfl_xor(s, m); ss += __shfl_xor(ss, m); }
  __shared__ float red[8];
  const int w = t >> 6, ln = t & 63;
  if (ln == 0) { red[w] = s; red[4 + w] = ss; }
  __syncthreads();
  s = red[0] + red[1] + red[2] + red[3];
  ss = red[4] + red[5] + red[6] + red[7];
  const float mu = s * (1.f / D_);
  const float rstd = rsqrtf(ss * (1.f / D_) - mu * mu + 1e-5f);
  f32x4 scv = *(const f32x4*)(sc + t * 4);
  f32x4 biv = *(const f32x4*)(bi + t * 4);
  bf16x4 yb;
  #pragma unroll
  for (int j = 0; j < 4; ++j) yb[j] = (bf16)((x[j] - mu) * rstd * scv[j] + biv[j]);
  *(bf16x4*)(hbout + off) = yb;
}

// ---------------- mean-pool (2-stage) + FC ----------------
__global__ __launch_bounds__(256)
void k_pool1(const bf16* __restrict__ h, float* __restrict__ part) {
  const int i = blockIdx.x * 256 + threadIdx.x;
  const int b = i >> 10, d = i & 1023;
  const int s0 = blockIdx.y * 128;
  float s = 0.f;
  for (int t = 0; t < 128; ++t) s += (float)h[((long)b * S_ + s0 + t) * D_ + d];
  part[(long)blockIdx.y * NTOK + i] = s;
}

__global__ __launch_bounds__(256)
void k_pool2(const float* __restrict__ part, float* __restrict__ pooled) {
  const int i = blockIdx.x * 256 + threadIdx.x;
  float s = 0.f;
  #pragma unroll
  for (int j = 0; j < 8; ++j) s += part[(long)j * NTOK + i];
  pooled[i] = s * (1.f / S_);
}

__global__ __launch_bounds__(64)
void k_fc(const float* __restrict__ pooled, const float* __restrict__ fw,
          const float* __restrict__ fb, float* __restrict__ out) {
  const int b = blockIdx.x / 10, c = blockIdx.x % 10;
  const int lane = threadIdx.x;
  float s = 0.f;
  for (int d = lane; d < D_; d += 64) s += pooled[b * D_ + d] * fw[d * 10 + c];
  #pragma unroll
  for (int m = 1; m < 64; m <<= 1) s += __shfl_xor(s, m);
  if (lane == 0) out[b * 10 + c] = s + fb[c];
}

// ---------------- host launcher ----------------
extern "C" void kernel_launch(void* const* d_in, const int* in_sizes, int n_in,
                              void* d_out, int out_size, void* d_ws, size_t ws_size,
                              hipStream_t stream) {
  const float* x     = (const float*)d_in[0];
  const float* emb_w = (const float*)d_in[1];
  const float* emb_b = (const float*)d_in[2];
  const float* Wq    = (const float*)d_in[3];
  const float* bq    = (const float*)d_in[4];
  const float* Wk    = (const float*)d_in[5];
  const float* bk    = (const float*)d_in[6];
  const float* Wv    = (const float*)d_in[7];
  const float* bv    = (const float*)d_in[8];
  const float* Wo    = (const float*)d_in[9];
  const float* bo    = (const float*)d_in[10];
  const float* W1    = (const float*)d_in[11];
  const float* b1    = (const float*)d_in[12];
  const float* W2    = (const float*)d_in[13];
  const float* b2    = (const float*)d_in[14];
  const float* ln1s  = (const float*)d_in[15];
  const float* ln1b  = (const float*)d_in[16];
  const float* ln2s  = (const float*)d_in[17];
  const float* ln2b  = (const float*)d_in[18];
  const float* fcw   = (const float*)d_in[19];
  const float* fcb   = (const float*)d_in[20];

  char* w = (char*)d_ws;
  size_t off = 0;
  auto alloc = [&](size_t bytes) -> char* {
    char* p = w + off;
    off += (bytes + 255) & ~(size_t)255;
    return p;
  };
  bf16*  x_bf  = (bf16*) alloc((size_t)NTOK * IND * 2);
  bf16*  embT  = (bf16*) alloc((size_t)D_ * IND * 2);
  bf16*  qkvT  = (bf16*) alloc((size_t)L_ * 3 * D_ * D_ * 2);
  bf16*  woT   = (bf16*) alloc((size_t)L_ * D_ * D_ * 2);
  bf16*  w1T   = (bf16*) alloc((size_t)L_ * FF * D_ * 2);
  bf16*  w2T   = (bf16*) alloc((size_t)L_ * D_ * FF * 2);
  float* qkvB  = (float*)alloc((size_t)L_ * 3 * D_ * 4);
  float* pe    = (float*)alloc((size_t)B_ * D_ * 4);
  bf16*  h_b   = (bf16*) alloc((size_t)NTOK * D_ * 2);
  bf16*  delta = (bf16*) alloc((size_t)NTOK * D_ * 2);
  float* pooled= (float*)alloc((size_t)B_ * D_ * 4);
  float* part  = (float*)alloc((size_t)8 * NTOK * 4);
  bf16*  scratch = (bf16*)alloc((size_t)NTOK * FF * 2);
  bf16* qb  = scratch;
  bf16* kb  = scratch + (size_t)NTOK * D_;
  bf16* vTb = scratch + (size_t)2 * NTOK * D_;
  bf16* ob  = scratch + (size_t)3 * NTOK * D_;
  bf16* ffn1 = scratch;
  bf16* p0 = (bf16*)alloc((size_t)NTOK * D_ * 2);
  bf16* p1 = (bf16*)alloc((size_t)NTOK * D_ * 2);
  const bool canSplit = (off <= ws_size);
  (void)in_sizes; (void)n_in; (void)out_size;

  k_f2b<<<dim3(NTOK * IND / 1024), dim3(256), 0, stream>>>(x, x_bf);
  k_trans<<<dim3(D_ / 64, IND / 64, 1), dim3(256), 0, stream>>>(emb_w, embT, IND, D_, 0, 0);
  k_trans<<<dim3(D_ / 64, D_ / 64, L_), dim3(256), 0, stream>>>(Wq, qkvT,               D_, D_, (long)D_ * D_, (long)3 * D_ * D_);
  k_trans<<<dim3(D_ / 64, D_ / 64, L_), dim3(256), 0, stream>>>(Wk, qkvT + D_ * D_,     D_, D_, (long)D_ * D_, (long)3 * D_ * D_);
  k_trans<<<dim3(D_ / 64, D_ / 64, L_), dim3(256), 0, stream>>>(Wv, qkvT + 2 * D_ * D_, D_, D_, (long)D_ * D_, (long)3 * D_ * D_);
  k_trans<<<dim3(D_ / 64, D_ / 64, L_), dim3(256), 0, stream>>>(Wo, woT, D_, D_, (long)D_ * D_, (long)D_ * D_);
  k_trans<<<dim3(FF / 64, D_ / 64, L_), dim3(256), 0, stream>>>(W1, w1T, D_, FF, (long)D_ * FF, (long)FF * D_);
  k_trans<<<dim3(D_ / 64, FF / 64, L_), dim3(256), 0, stream>>>(W2, w2T, FF, D_, (long)FF * D_, (long)D_ * FF);
  k_pe<<<dim3(B_ * D_ / 256), dim3(256), 0, stream>>>(pe);
  k_packb<<<dim3(L_ * 3 * D_ / 256), dim3(256), 0, stream>>>(bq, bk, bv, qkvB);

  k_gemm<3><<<dim3(D_ / 128, NTOK / 128), dim3(256), 0, stream>>>(
      x_bf, embT, emb_b, nullptr, h_b, pe, NTOK, D_, IND);

  for (int l = 0; l < L_; ++l) {
    k_gemm256<2, 0><<<dim3(3 * D_ / 256, NTOK / 256), dim3(512), 0, stream>>>(
        h_b, qkvT + (size_t)l * 3 * D_ * D_, qkvB + l * 3 * D_,
        qb, vTb, nullptr, nullptr, NTOK, 3 * D_, D_);
    k_flash<<<dim3(S_ / 64, B_ * H_), dim3(256), 0, stream>>>(qb, kb, vTb, ob);
    if (canSplit) {
      k_gemm256<0, 1><<<dim3(D_ / 256, NTOK / 256, 2), dim3(512), 0, stream>>>(
          ob, woT + (size_t)l * D_ * D_, nullptr,
          nullptr, nullptr, p0, p1, NTOK, D_, D_);
      k_addln<1><<<dim3(NTOK), dim3(256), 0, stream>>>(
          h_b, nullptr, p0, p1, bo + l * D_, ln1s + l * D_, ln1b + l * D_, h_b);
    } else {
      k_gemm256<0, 0><<<dim3(D_ / 256, NTOK / 256), dim3(512), 0, stream>>>(
          ob, woT + (size_t)l * D_ * D_, bo + l * D_,
          delta, nullptr, nullptr, nullptr, NTOK, D_, D_);
      k_addln<0><<<dim3(NTOK), dim3(256), 0, stream>>>(
          h_b, delta, nullptr, nullptr, nullptr, ln1s + l * D_, ln1b + l * D_, h_b);
    }
    k_gemm256<1, 0><<<dim3(FF / 256, NTOK / 256), dim3(512), 0, stream>>>(
        h_b, w1T + (size_t)l * FF * D_, b1 + l * FF,
        ffn1, nullptr, nullptr, nullptr, NTOK, FF, D_);
    if (canSplit) {
      k_gemm256<0, 1><<<dim3(D_ / 256, NTOK / 256, 2), dim3(512), 0, stream>>>(
          ffn1, w2T + (size_t)l * D_ * FF, nullptr,
          nullptr, nullptr, p0, p1, NTOK, D_, FF);
      k_addln<1><<<dim3(NTOK), dim3(256), 0, stream>>>(
          h_b, nullptr, p0, p1, b2 + l * D_, ln2s + l * D_, ln2b + l * D_, h_b);
    } else {
      k_gemm256<0, 0><<<dim3(D_ / 256, NTOK / 256), dim3(512), 0, stream>>>(
          ffn1, w2T + (size_t)l * D_ * FF, b2 + l * D_,
          delta, nullptr, nullptr, nullptr, NTOK, D_, FF);
      k_addln<0><<<dim3(NTOK), dim3(256), 0, stream>>>(
          h_b, delta, nullptr, nullptr, nullptr, ln2s + l * D_, ln2b + l * D_, h_b);
    }
  }

  k_pool1<<<dim3(NTOK / 256, 8), dim3(256), 0, stream>>>(h_b, part);
  k_pool2<<<dim3(NTOK / 256), dim3(256), 0, stream>>>(part, pooled);
  k_fc<<<dim3(B_ * 10), dim3(64), 0, stream>>>(pooled, fcw, fcb, (float*)d_out);
}

// Round 16
// 2177.503 us; speedup vs baseline: 1.1422x; 1.0035x over previous
//
#include <hip/hip_runtime.h>
#include <stdint.h>

#define B_   8
#define S_   1024
#define IND  256
#define D_   1024
#define H_   16
#define DKH  64
#define L_   6
#define FF   4096
#define NTOK (B_*S_)

typedef __bf16 bf16;
typedef __attribute__((ext_vector_type(4))) float  f32x4;
typedef __attribute__((ext_vector_type(16))) float f32x16;
typedef __attribute__((ext_vector_type(8))) __bf16 bf16x8;
typedef __attribute__((ext_vector_type(4))) __bf16 bf16x4;
typedef __attribute__((ext_vector_type(2))) __bf16 bf16x2;

#define AS1 __attribute__((address_space(1)))
#define AS3 __attribute__((address_space(3)))

__device__ __forceinline__ void gload16(const void* g, void* l) {
  __builtin_amdgcn_global_load_lds((AS1 void*)(const_cast<void*>(g)), (AS3 void*)l, 16, 0, 0);
}

// ---------------- weight transpose+convert: in [K][N] f32 -> out [N][K] bf16 ----------------
__global__ __launch_bounds__(256)
void k_trans(const float* __restrict__ in, bf16* __restrict__ out,
             int K, int N, long inStride, long outStride) {
  __shared__ float t[64][65];
  const float* inp = in + (long)blockIdx.z * inStride;
  bf16* outp = out + (long)blockIdx.z * outStride;
  const int n0 = blockIdx.x * 64, k0 = blockIdx.y * 64;
  const int r = threadIdx.x >> 4;
  const int c4 = (threadIdx.x & 15) * 4;
  #pragma unroll
  for (int j = 0; j < 64; j += 16) {
    f32x4 v = *(const f32x4*)(inp + (long)(k0 + r + j) * N + n0 + c4);
    #pragma unroll
    for (int i = 0; i < 4; ++i) t[r + j][c4 + i] = v[i];
  }
  __syncthreads();
  #pragma unroll
  for (int j = 0; j < 64; j += 16) {
    const int n = r + j;
    bf16x4 o;
    #pragma unroll
    for (int i = 0; i < 4; ++i) o[i] = (bf16)t[c4 + i][n];
    *(bf16x4*)(outp + (long)(n0 + n) * K + k0 + c4) = o;
  }
}

// ---------------- fp32 -> bf16 elementwise ----------------
__global__ __launch_bounds__(256)
void k_f2b(const float* __restrict__ in, bf16* __restrict__ out) {
  const long i = ((long)blockIdx.x * 256 + threadIdx.x) * 4;
  f32x4 v = *(const f32x4*)(in + i);
  bf16x4 o;
  #pragma unroll
  for (int j = 0; j < 4; ++j) o[j] = (bf16)v[j];
  *(bf16x4*)(out + i) = o;
}

// ---------------- positional encoding rows ----------------
__global__ __launch_bounds__(256)
void k_pe(float* __restrict__ pe) {
  const int i = blockIdx.x * 256 + threadIdx.x;
  const int b = i >> 10, d = i & 1023;
  const float k2 = (float)(d & ~1);
  const float dv = __expf(k2 * (-9.210340371976184f / (float)D_));
  const float a = (float)b * dv;
  pe[i] = (d & 1) ? cosf(a) : sinf(a);
}

// ---------------- pack per-layer qkv bias [L][3072] ----------------
__global__ __launch_bounds__(256)
void k_packb(const float* __restrict__ bq, const float* __restrict__ bk,
             const float* __restrict__ bv, float* __restrict__ out) {
  const int i = blockIdx.x * 256 + threadIdx.x;
  const int l = i / 3072, j = i % 3072;
  const float* src = (j < 1024) ? bq : ((j < 2048) ? bk : bv);
  out[i] = src[l * 1024 + (j & 1023)];
}

// ---------------- 128^2 GEMM — embedding (EPI 3: +pe, bf16 out) ----------------
template<int EPI>
__global__ __launch_bounds__(256)
void k_gemm(const bf16* __restrict__ A, const bf16* __restrict__ Bt,
            const float* __restrict__ bias,
            void* __restrict__ out0, void* __restrict__ out1,
            const float* __restrict__ pe,
            int M, int N, int K) {
  __shared__ __align__(16) bf16 sA[128 * 32];
  __shared__ __align__(16) bf16 sB[128 * 32];
  const int tid = threadIdx.x;
  const int lane = tid & 63, wv = tid >> 6;
  const int bx = blockIdx.x, by = blockIdx.y;
  const int wm = wv >> 1, wn = wv & 1;
  const int lg = lane >> 4, lc = lane & 15;
  const long arow0 = (long)by * 128;
  const long brow0 = (long)bx * 128;
  const int c0 = (wv * 2 + 0) * 64 + lane;
  const int c1 = (wv * 2 + 1) * 64 + lane;
  const int r0 = c0 >> 2, s0 = c0 & 3;
  const int r1 = c1 >> 2, s1 = c1 & 3;
  bf16* ldsA0 = sA + (wv * 2 + 0) * 512;
  bf16* ldsA1 = sA + (wv * 2 + 1) * 512;
  bf16* ldsB0 = sB + (wv * 2 + 0) * 512;
  bf16* ldsB1 = sB + (wv * 2 + 1) * 512;
  const bf16* Ab = A + arow0 * K;
  const bf16* Bb = Bt + brow0 * K;
  f32x4 acc[4][4] = {};
  const int kT = K >> 5;
  for (int kt = 0; kt < kT; ++kt) {
    const int k0 = kt << 5;
    gload16(Ab + (long)r0 * K + k0 + s0 * 8, ldsA0);
    gload16(Ab + (long)r1 * K + k0 + s1 * 8, ldsA1);
    gload16(Bb + (long)r0 * K + k0 + s0 * 8, ldsB0);
    gload16(Bb + (long)r1 * K + k0 + s1 * 8, ldsB1);
    __syncthreads();
    bf16x8 af[4], bfr[4];
    #pragma unroll
    for (int mr = 0; mr < 4; ++mr)
      af[mr] = *(const bf16x8*)(sA + (wm * 64 + mr * 16 + lc) * 32 + lg * 8);
    #pragma unroll
    for (int nc = 0; nc < 4; ++nc)
      bfr[nc] = *(const bf16x8*)(sB + (wn * 64 + nc * 16 + lc) * 32 + lg * 8);
    #pragma unroll
    for (int mr = 0; mr < 4; ++mr)
      #pragma unroll
      for (int nc = 0; nc < 4; ++nc)
        acc[mr][nc] = __builtin_amdgcn_mfma_f32_16x16x32_bf16(af[mr], bfr[nc], acc[mr][nc], 0, 0, 0);
    __syncthreads();
  }
  #pragma unroll
  for (int mr = 0; mr < 4; ++mr) {
    const int row0 = by * 128 + wm * 64 + mr * 16 + lg * 4;
    #pragma unroll
    for (int nc = 0; nc < 4; ++nc) {
      const int col = bx * 128 + wn * 64 + nc * 16 + lc;
      const float bvv = bias[col];
      #pragma unroll
      for (int r = 0; r < 4; ++r) {
        float v = acc[mr][nc][r] + bvv;
        const long rr = row0 + r;
        if constexpr (EPI == 0) {
          ((bf16*)out0)[rr * N + col] = (bf16)v;
        } else {
          const long bb = rr >> 10;
          v += pe[bb * D_ + col];
          ((bf16*)out1)[rr * N + col] = (bf16)v;
        }
      }
    }
  }
}

// ---------------- 256^2 8-phase GEMM (R5 schedule — banked best) ----------------
template<int EPI, int SPLIT>
__global__ __launch_bounds__(512, 2)
void k_gemm256(const bf16* __restrict__ A, const bf16* __restrict__ Bt,
               const float* __restrict__ bias,
               void* __restrict__ out0, void* __restrict__ out1,
               bf16* __restrict__ pout0, bf16* __restrict__ pout1,
               int M, int N, int K) {
  __shared__ __align__(16) bf16 lds[65536];
  const int tid = threadIdx.x;
  const int lane = tid & 63, wv = tid >> 6;
  const int wm = wv >> 2, wn = wv & 3;
  const int lg = lane >> 4, lc = lane & 15;
  const int gx = gridDim.x;
  const int nwg = gx * gridDim.y;
  int bid = blockIdx.x + blockIdx.y * gx;
  const int cpx = nwg >> 3;
  bid = (bid & 7) * cpx + (bid >> 3);
  const int bxs = bid % gx, bys = bid / gx;
  const int tileRow = bys * 256, tileCol = bxs * 256;
  const int kPart = SPLIT ? (K >> 1) : K;
  const long kOff = SPLIT ? (long)blockIdx.z * kPart : 0;
  const bf16* Abase = A + (long)tileRow * K + kOff;
  const bf16* Bbase = Bt + (long)tileCol * K + kOff;
  const long laneOff = (long)lc * K + lg * 8;
  f32x4 acc[8][4] = {};
  const int NT = kPart >> 6;
  const int NI = NT >> 1;

  auto stA = [&](int t, int h, int bb) {
    const int rg = h * 16 + wv * 2;
    const int mb = rg >> 1;
    const bf16* s = Abase + (long)(mb * 16) * K + t * 64 + laneOff;
    bf16* d = lds + bb * 32768 + rg * 512;
    gload16(s, d);
    gload16(s + 32, d + 512);
  };
  auto stB = [&](int t, int h, int bb) {
    const int rg = h * 16 + wv * 2;
    const int mb = rg >> 1;
    const bf16* s = Bbase + (long)(mb * 16) * K + t * 64 + laneOff;
    bf16* d = lds + bb * 32768 + 16384 + rg * 512;
    gload16(s, d);
    gload16(s + 32, d + 512);
  };

  bf16x8 aF[8];
  bf16x8 bF0[4], bF1[4];

#define LDA(BB, MH) do { _Pragma("unroll") for (int m = 0; m < 4; ++m) \
    _Pragma("unroll") for (int kk = 0; kk < 2; ++kk) \
      aF[m*2+kk] = *(const bf16x8*)(lds + (BB)*32768 + ((wm*8 + (MH)*4 + m)*2 + kk)*512 + lane*8); \
  } while(0)
#define LDB(BB, NH, DST) do { _Pragma("unroll") for (int n = 0; n < 2; ++n) \
    _Pragma("unroll") for (int kk = 0; kk < 2; ++kk) \
      DST[n*2+kk] = *(const bf16x8*)(lds + (BB)*32768 + 16384 + ((wn*4 + (NH)*2 + n)*2 + kk)*512 + lane*8); \
  } while(0)
#define MMA(MH, NH, BSRC) do { \
    __builtin_amdgcn_s_setprio(1); \
    _Pragma("unroll") for (int m = 0; m < 4; ++m) \
      _Pragma("unroll") for (int n = 0; n < 2; ++n) { \
        acc[(MH)*4+m][(NH)*2+n] = __builtin_amdgcn_mfma_f32_16x16x32_bf16(aF[m*2+0], BSRC[n*2+0], acc[(MH)*4+m][(NH)*2+n], 0, 0, 0); \
        acc[(MH)*4+m][(NH)*2+n] = __builtin_amdgcn_mfma_f32_16x16x32_bf16(aF[m*2+1], BSRC[n*2+1], acc[(MH)*4+m][(NH)*2+n], 0, 0, 0); \
      } \
    __builtin_amdgcn_s_setprio(0); \
  } while(0)
#define VM8 asm volatile("s_waitcnt vmcnt(8)" ::: "memory")
#define VM0 asm volatile("s_waitcnt vmcnt(0)" ::: "memory")
#define BAR __builtin_amdgcn_s_barrier()

  stA(0, 0, 0); stB(0, 0, 0); stA(0, 1, 0); stB(0, 1, 0);
  stA(1, 0, 1); stB(1, 0, 1); stA(1, 1, 1); stB(1, 1, 1);

  for (int i = 0; i < NI - 1; ++i) {
    const int t2 = 2 * i + 2, t3 = 2 * i + 3;
    VM8; BAR; LDA(0, 0); LDB(0, 0, bF0);   MMA(0, 0, bF0);
         BAR; LDB(0, 1, bF1); stA(t2, 0, 0);              MMA(0, 1, bF1);
         BAR; LDA(0, 1);      stB(t2, 0, 0);              MMA(1, 0, bF0);
         BAR; stA(t2, 1, 0);  stB(t2, 1, 0);              MMA(1, 1, bF1);
    VM8; BAR; LDA(1, 0); LDB(1, 0, bF0);   MMA(0, 0, bF0);
         BAR; LDB(1, 1, bF1); stA(t3, 0, 1);              MMA(0, 1, bF1);
         BAR; LDA(1, 1);      stB(t3, 0, 1);              MMA(1, 0, bF0);
         BAR; stA(t3, 1, 1);  stB(t3, 1, 1);              MMA(1, 1, bF1);
  }
  {
    VM8; BAR; LDA(0, 0); LDB(0, 0, bF0); MMA(0, 0, bF0);
         BAR; LDB(0, 1, bF1);            MMA(0, 1, bF1);
         BAR; LDA(0, 1);                 MMA(1, 0, bF0);
         BAR;                            MMA(1, 1, bF1);
    VM0; BAR; LDA(1, 0); LDB(1, 0, bF0); MMA(0, 0, bF0);
         BAR; LDB(1, 1, bF1);            MMA(0, 1, bF1);
         BAR; LDA(1, 1);                 MMA(1, 0, bF0);
         BAR;                            MMA(1, 1, bF1);
  }
#undef LDA
#undef LDB
#undef MMA
#undef VM8
#undef VM0
#undef BAR

  #pragma unroll
  for (int mr = 0; mr < 8; ++mr) {
    const int row0 = tileRow + wm * 128 + mr * 16 + lg * 4;
    #pragma unroll
    for (int nr = 0; nr < 4; ++nr) {
      const int col = tileCol + wn * 64 + nr * 16 + lc;
      if constexpr (SPLIT) {
        bf16* po = blockIdx.z ? pout1 : pout0;
        #pragma unroll
        for (int r = 0; r < 4; ++r)
          po[(long)(row0 + r) * N + col] = (bf16)acc[mr][nr][r];
      } else if constexpr (EPI == 2) {
        const float bvv = bias[col];
        const int which = col >> 10;
        const int hh = (col & 1023) >> 6;
        const int dk = col & 63;
        const long bb = row0 >> 10;
        const int sr = row0 & 1023;
        if (which == 2) {
          bf16x4 pk;
          #pragma unroll
          for (int r = 0; r < 4; ++r) pk[r] = (bf16)(acc[mr][nr][r] + bvv);
          *(bf16x4*)((bf16*)out1 + ((bb * H_ + hh) * (long)DKH + dk) * S_ + sr) = pk;
        } else {
          #pragma unroll
          for (int r = 0; r < 4; ++r) {
            float v = acc[mr][nr][r] + bvv;
            if (which == 0) v *= 0.125f;
            ((bf16*)out0)[(long)which * NTOK * D_ + ((bb * H_ + hh) * (long)S_ + sr + r) * DKH + dk] = (bf16)v;
          }
        }
      } else {
        const float bvv = bias[col];
        #pragma unroll
        for (int r = 0; r < 4; ++r) {
          float v = acc[mr][nr][r] + bvv;
          const long rr = row0 + r;
          if constexpr (EPI == 1) v = fmaxf(v, 0.f);
          ((bf16*)out0)[rr * N + col] = (bf16)v;
        }
      }
    }
  }
}

// ---------------- 256^2 8-phase GEMM with 32x32x16 MFMA (A/B on FFN1, relu epilogue) ----------------
// Same R5 schedule/staging volume; region = [32 rows][16 k] 1KB, slot l holds (row=l&31, kh=l>>5)
// -> linear gload dest + linear ds_read_b128 at region+lane*16 (conflict-free, rule 21 both-sides).
// A-frag: row=lane&31, k=(lane>>5)*8 contiguous; C/D: col=lane&31, row=(reg&3)+8*(reg>>2)+4*(lane>>5).
__global__ __launch_bounds__(512, 2)
void k_gemm32(const bf16* __restrict__ A, const bf16* __restrict__ Bt,
              const float* __restrict__ bias,
              bf16* __restrict__ out0,
              int M, int N, int K) {
  __shared__ __align__(16) bf16 lds[65536];
  const int tid = threadIdx.x;
  const int lane = tid & 63, wv = tid >> 6;
  const int wm = wv >> 2, wn = wv & 3;
  const int l31 = lane & 31, lh = lane >> 5;
  const int gx = gridDim.x;
  const int nwg = gx * gridDim.y;
  int bid = blockIdx.x + blockIdx.y * gx;
  const int cpx = nwg >> 3;
  bid = (bid & 7) * cpx + (bid >> 3);
  const int bxs = bid % gx, bys = bid / gx;
  const int tileRow = bys * 256, tileCol = bxs * 256;
  const bf16* Abase = A + (long)tileRow * K;
  const bf16* Bbase = Bt + (long)tileCol * K;
  const long laneOff = (long)l31 * K + lh * 8;
  f32x16 acc[4][2] = {};
  const int NT = K >> 6;
  const int NI = NT >> 1;

  auto stA = [&](int t, int h, int bb) {
    #pragma unroll
    for (int j = 0; j < 2; ++j) {
      const int rg = h * 16 + wv * 2 + j;
      const int mf = rg >> 2, ks = rg & 3;
      const bf16* s = Abase + (long)(mf * 32) * K + t * 64 + ks * 16 + laneOff;
      gload16(s, lds + bb * 32768 + rg * 512);
    }
  };
  auto stB = [&](int t, int h, int bb) {
    #pragma unroll
    for (int j = 0; j < 2; ++j) {
      const int rg = h * 16 + wv * 2 + j;
      const int nf = rg >> 2, ks = rg & 3;
      const bf16* s = Bbase + (long)(nf * 32) * K + t * 64 + ks * 16 + laneOff;
      gload16(s, lds + bb * 32768 + 16384 + rg * 512);
    }
  };

  bf16x8 aF[8];
  bf16x8 bF0[4], bF1[4];

#define LDA32(BB, MH) do { _Pragma("unroll") for (int j = 0; j < 2; ++j) \
    _Pragma("unroll") for (int ks = 0; ks < 4; ++ks) { \
      const int mf = wm * 4 + (MH) * 2 + j; \
      aF[j*4+ks] = *(const bf16x8*)(lds + (BB)*32768 + (mf*4+ks)*512 + lane*8); \
    } } while(0)
#define LDB32(BB, NH, DST) do { const int nf = wn * 2 + (NH); \
    _Pragma("unroll") for (int ks = 0; ks < 4; ++ks) \
      DST[ks] = *(const bf16x8*)(lds + (BB)*32768 + 16384 + (nf*4+ks)*512 + lane*8); \
  } while(0)
#define MMA32(MH, NH, BSRC) do { \
    __builtin_amdgcn_s_setprio(1); \
    _Pragma("unroll") for (int j = 0; j < 2; ++j) \
      _Pragma("unroll") for (int ks = 0; ks < 4; ++ks) \
        acc[(MH)*2+j][NH] = __builtin_amdgcn_mfma_f32_32x32x16_bf16(aF[j*4+ks], BSRC[ks], acc[(MH)*2+j][NH], 0, 0, 0); \
    __builtin_amdgcn_s_setprio(0); \
  } while(0)
#define VM8 asm volatile("s_waitcnt vmcnt(8)" ::: "memory")
#define VM0 asm volatile("s_waitcnt vmcnt(0)" ::: "memory")
#define BAR __builtin_amdgcn_s_barrier()

  stA(0, 0, 0); stB(0, 0, 0); stA(0, 1, 0); stB(0, 1, 0);
  stA(1, 0, 1); stB(1, 0, 1); stA(1, 1, 1); stB(1, 1, 1);

  for (int i = 0; i < NI - 1; ++i) {
    const int t2 = 2 * i + 2, t3 = 2 * i + 3;
    VM8; BAR; LDA32(0, 0); LDB32(0, 0, bF0);   MMA32(0, 0, bF0);
         BAR; LDB32(0, 1, bF1); stA(t2, 0, 0);              MMA32(0, 1, bF1);
         BAR; LDA32(0, 1);      stB(t2, 0, 0);              MMA32(1, 0, bF0);
         BAR; stA(t2, 1, 0);  stB(t2, 1, 0);                MMA32(1, 1, bF1);
    VM8; BAR; LDA32(1, 0); LDB32(1, 0, bF0);   MMA32(0, 0, bF0);
         BAR; LDB32(1, 1, bF1); stA(t3, 0, 1);              MMA32(0, 1, bF1);
         BAR; LDA32(1, 1);      stB(t3, 0, 1);              MMA32(1, 0, bF0);
         BAR; stA(t3, 1, 1);  stB(t3, 1, 1);                MMA32(1, 1, bF1);
  }
  {
    VM8; BAR; LDA32(0, 0); LDB32(0, 0, bF0); MMA32(0, 0, bF0);
         BAR; LDB32(0, 1, bF1);              MMA32(0, 1, bF1);
         BAR; LDA32(0, 1);                   MMA32(1, 0, bF0);
         BAR;                                MMA32(1, 1, bF1);
    VM0; BAR; LDA32(1, 0); LDB32(1, 0, bF0); MMA32(0, 0, bF0);
         BAR; LDB32(1, 1, bF1);              MMA32(0, 1, bF1);
         BAR; LDA32(1, 1);                   MMA32(1, 0, bF0);
         BAR;                                MMA32(1, 1, bF1);
  }
#undef LDA32
#undef LDB32
#undef MMA32
#undef VM8
#undef VM0
#undef BAR

  // epilogue: relu + bias; C/D layout col=lane&31, row=(reg&3)+8*(reg>>2)+4*lh
  #pragma unroll
  for (int mf = 0; mf < 4; ++mf) {
    const int rowb = tileRow + wm * 128 + mf * 32 + lh * 4;
    #pragma unroll
    for (int nf = 0; nf < 2; ++nf) {
      const int col = tileCol + wn * 64 + nf * 32 + l31;
      const float bvv = bias[col];
      #pragma unroll
      for (int g = 0; g < 4; ++g)
        #pragma unroll
        for (int r = 0; r < 4; ++r) {
          float v = acc[mf][nf][g * 4 + r] + bvv;
          v = fmaxf(v, 0.f);
          out0[(long)(rowb + g * 8 + r) * N + col] = (bf16)v;
        }
    }
  }
}

// ---------------- flash attention (XCD-swizzled) ----------------
__global__ __launch_bounds__(256)
void k_flash(const bf16* __restrict__ qg, const bf16* __restrict__ kgl,
             const bf16* __restrict__ vtg, bf16* __restrict__ og) {
  __shared__ __align__(16) bf16 sK[64 * 64];
  __shared__ __align__(16) bf16 sV[64 * 64];
  __shared__ __align__(16) bf16 sP[4 * 16 * 64];
  const int tid = threadIdx.x, lane = tid & 63, wv = tid >> 6;
  const int lg = lane >> 4, lc = lane & 15;
  int bid = blockIdx.x + blockIdx.y * 16;
  bid = (bid & 7) * 256 + (bid >> 3);
  const int qt = bid & 15, bh = bid >> 4;
  const long base = (long)bh * S_ * DKH;
  const bf16* qb = qg + base;
  const bf16* kb = kgl + base;
  const bf16* vb = vtg + base;
  const int qrow = qt * 64 + wv * 16 + lc;
  const bf16x8 qf0 = *(const bf16x8*)(qb + (long)qrow * DKH + lg * 8);
  const bf16x8 qf1 = *(const bf16x8*)(qb + (long)qrow * DKH + 32 + lg * 8);
  float mrun = -3e38f, lrun = 0.f;
  f32x4 oacc[4] = {};
  bf16* sPw = sP + wv * (16 * 64);
  const int swzP = (lc & 7) << 4;
  const int c0 = wv * 128 + lane, c1 = c0 + 64;
  const int r0 = c0 >> 3, sl0 = (c0 & 7) ^ (r0 & 7);
  const int r1 = c1 >> 3, sl1 = (c1 & 7) ^ (r1 & 7);
  bf16* dst0 = sK + c0 * 8 - lane * 8;
  bf16* dst1 = sK + c1 * 8 - lane * 8;
  bf16* dstV0 = sV + c0 * 8 - lane * 8;
  bf16* dstV1 = sV + c1 * 8 - lane * 8;
  for (int kt = 0; kt < S_ / 64; ++kt) {
    const int gk = kt * 64;
    gload16(kb + (long)(gk + r0) * DKH + sl0 * 8, dst0);
    gload16(kb + (long)(gk + r1) * DKH + sl1 * 8, dst1);
    gload16(vb + (long)r0 * S_ + gk + sl0 * 8, dstV0);
    gload16(vb + (long)r1 * S_ + gk + sl1 * 8, dstV1);
    __syncthreads();
    f32x4 sacc[4] = {};
    #pragma unroll
    for (int nc = 0; nc < 4; ++nc) {
      const int kr = nc * 16 + lc;
      bf16x8 k0 = *(const bf16x8*)((char*)sK + kr * 128 + (((0 + lg) ^ (kr & 7)) << 4));
      bf16x8 k1 = *(const bf16x8*)((char*)sK + kr * 128 + (((4 + lg) ^ (kr & 7)) << 4));
      sacc[nc] = __builtin_amdgcn_mfma_f32_16x16x32_bf16(k0, qf0, sacc[nc], 0, 0, 0);
      sacc[nc] = __builtin_amdgcn_mfma_f32_16x16x32_bf16(k1, qf1, sacc[nc], 0, 0, 0);
    }
    float pm = sacc[0][0];
    #pragma unroll
    for (int nc = 0; nc < 4; ++nc)
      #pragma unroll
      for (int r = 0; r < 4; ++r) pm = fmaxf(pm, sacc[nc][r]);
    pm = fmaxf(pm, __shfl_xor(pm, 16));
    pm = fmaxf(pm, __shfl_xor(pm, 32));
    const float mnew = fmaxf(mrun, pm);
    const float fac = __expf(mrun - mnew);
    float ps = 0.f;
    #pragma unroll
    for (int nc = 0; nc < 4; ++nc)
      #pragma unroll
      for (int r = 0; r < 4; ++r) {
        const float p = __expf(sacc[nc][r] - mnew);
        sacc[nc][r] = p;
        ps += p;
      }
    ps += __shfl_xor(ps, 16);
    ps += __shfl_xor(ps, 32);
    lrun = lrun * fac + ps;
    mrun = mnew;
    #pragma unroll
    for (int nc = 0; nc < 4; ++nc)
      #pragma unroll
      for (int rp = 0; rp < 2; ++rp) {
        bf16x2 t;
        t[0] = (bf16)sacc[nc][rp * 2 + 0];
        t[1] = (bf16)sacc[nc][rp * 2 + 1];
        *(bf16x2*)((char*)sPw + lc * 128 + ((nc * 32 + lg * 8 + rp * 4) ^ swzP)) = t;
      }
    asm volatile("s_waitcnt lgkmcnt(0)" ::: "memory");
    __builtin_amdgcn_sched_barrier(0);
    float fr[4];
    #pragma unroll
    for (int r = 0; r < 4; ++r) fr[r] = __shfl(fac, lg * 4 + r);
    #pragma unroll
    for (int nc = 0; nc < 4; ++nc)
      #pragma unroll
      for (int r = 0; r < 4; ++r) oacc[nc][r] *= fr[r];
    #pragma unroll
    for (int m = 0; m < 2; ++m) {
      const bf16x8 pf = *(const bf16x8*)((char*)sPw + lc * 128 + ((m * 64 + lg * 16) ^ swzP));
      #pragma unroll
      for (int nc = 0; nc < 4; ++nc) {
        const int vr = nc * 16 + lc;
        bf16x8 vf = *(const bf16x8*)((char*)sV + vr * 128 + (((m * 4 + lg) ^ (vr & 7)) << 4));
        oacc[nc] = __builtin_amdgcn_mfma_f32_16x16x32_bf16(pf, vf, oacc[nc], 0, 0, 0);
      }
    }
    __syncthreads();
  }
  const int b = bh >> 4, h = bh & 15;
  const float linv = 1.f / lrun;
  #pragma unroll
  for (int r = 0; r < 4; ++r) {
    const float inv = __shfl(linv, lg * 4 + r);
    const int s = qt * 64 + wv * 16 + lg * 4 + r;
    const long obase = (((long)b * S_ + s) * H_ + h) * DKH;
    #pragma unroll
    for (int nc = 0; nc < 4; ++nc)
      og[obase + nc * 16 + lc] = (bf16)(oacc[nc][r] * inv);
  }
}

// ---------------- fused residual add + LayerNorm (bf16 residual stream) ----------------
template<int TWO>
__global__ __launch_bounds__(256)
void k_addln(const bf16* __restrict__ hin, const bf16* __restrict__ dlt,
             const bf16* __restrict__ p0, const bf16* __restrict__ p1,
             const float* __restrict__ gb,
             const float* __restrict__ sc, const float* __restrict__ bi,
             bf16* __restrict__ hbout) {
  const int row = blockIdx.x, t = threadIdx.x;
  const long off = (long)row * D_ + t * 4;
  bf16x4 hv = *(const bf16x4*)(hin + off);
  f32x4 x;
  if constexpr (TWO) {
    bf16x4 a = *(const bf16x4*)(p0 + off);
    bf16x4 b = *(const bf16x4*)(p1 + off);
    f32x4 g = *(const f32x4*)(gb + t * 4);
    #pragma unroll
    for (int j = 0; j < 4; ++j) x[j] = (float)hv[j] + (float)a[j] + (float)b[j] + g[j];
  } else {
    bf16x4 dv = *(const bf16x4*)(dlt + off);
    #pragma unroll
    for (int j = 0; j < 4; ++j) x[j] = (float)hv[j] + (float)dv[j];
  }
  float s = 0.f, ss = 0.f;
  #pragma unroll
  for (int j = 0; j < 4; ++j) { s += x[j]; ss += x[j] * x[j]; }
  #pragma unroll
  for (int m = 1; m < 64; m <<= 1) { s += __shfl_xor(s, m); ss += __shfl_xor(ss, m); }
  __shared__ float red[8];
  const int w = t >> 6, ln = t & 63;
  if (ln == 0) { red[w] = s; red[4 + w] = ss; }
  __syncthreads();
  s = red[0] + red[1] + red[2] + red[3];
  ss = red[4] + red[5] + red[6] + red[7];
  const float mu = s * (1.f / D_);
  const float rstd = rsqrtf(ss * (1.f / D_) - mu * mu + 1e-5f);
  f32x4 scv = *(const f32x4*)(sc + t * 4);
  f32x4 biv = *(const f32x4*)(bi + t * 4);
  bf16x4 yb;
  #pragma unroll
  for (int j = 0; j < 4; ++j) yb[j] = (bf16)((x[j] - mu) * rstd * scv[j] + biv[j]);
  *(bf16x4*)(hbout + off) = yb;
}

// ---------------- mean-pool (2-stage) + FC ----------------
__global__ __launch_bounds__(256)
void k_pool1(const bf16* __restrict__ h, float* __restrict__ part) {
  const int i = blockIdx.x * 256 + threadIdx.x;
  const int b = i >> 10, d = i & 1023;
  const int s0 = blockIdx.y * 128;
  float s = 0.f;
  for (int t = 0; t < 128; ++t) s += (float)h[((long)b * S_ + s0 + t) * D_ + d];
  part[(long)blockIdx.y * NTOK + i] = s;
}

__global__ __launch_bounds__(256)
void k_pool2(const float* __restrict__ part, float* __restrict__ pooled) {
  const int i = blockIdx.x * 256 + threadIdx.x;
  float s = 0.f;
  #pragma unroll
  for (int j = 0; j < 8; ++j) s += part[(long)j * NTOK + i];
  pooled[i] = s * (1.f / S_);
}

__global__ __launch_bounds__(64)
void k_fc(const float* __restrict__ pooled, const float* __restrict__ fw,
          const float* __restrict__ fb, float* __restrict__ out) {
  const int b = blockIdx.x / 10, c = blockIdx.x % 10;
  const int lane = threadIdx.x;
  float s = 0.f;
  for (int d = lane; d < D_; d += 64) s += pooled[b * D_ + d] * fw[d * 10 + c];
  #pragma unroll
  for (int m = 1; m < 64; m <<= 1) s += __shfl_xor(s, m);
  if (lane == 0) out[b * 10 + c] = s + fb[c];
}

// ---------------- host launcher ----------------
extern "C" void kernel_launch(void* const* d_in, const int* in_sizes, int n_in,
                              void* d_out, int out_size, void* d_ws, size_t ws_size,
                              hipStream_t stream) {
  const float* x     = (const float*)d_in[0];
  const float* emb_w = (const float*)d_in[1];
  const float* emb_b = (const float*)d_in[2];
  const float* Wq    = (const float*)d_in[3];
  const float* bq    = (const float*)d_in[4];
  const float* Wk    = (const float*)d_in[5];
  const float* bk    = (const float*)d_in[6];
  const float* Wv    = (const float*)d_in[7];
  const float* bv    = (const float*)d_in[8];
  const float* Wo    = (const float*)d_in[9];
  const float* bo    = (const float*)d_in[10];
  const float* W1    = (const float*)d_in[11];
  const float* b1    = (const float*)d_in[12];
  const float* W2    = (const float*)d_in[13];
  const float* b2    = (const float*)d_in[14];
  const float* ln1s  = (const float*)d_in[15];
  const float* ln1b  = (const float*)d_in[16];
  const float* ln2s  = (const float*)d_in[17];
  const float* ln2b  = (const float*)d_in[18];
  const float* fcw   = (const float*)d_in[19];
  const float* fcb   = (const float*)d_in[20];

  char* w = (char*)d_ws;
  size_t off = 0;
  auto alloc = [&](size_t bytes) -> char* {
    char* p = w + off;
    off += (bytes + 255) & ~(size_t)255;
    return p;
  };
  bf16*  x_bf  = (bf16*) alloc((size_t)NTOK * IND * 2);
  bf16*  embT  = (bf16*) alloc((size_t)D_ * IND * 2);
  bf16*  qkvT  = (bf16*) alloc((size_t)L_ * 3 * D_ * D_ * 2);
  bf16*  woT   = (bf16*) alloc((size_t)L_ * D_ * D_ * 2);
  bf16*  w1T   = (bf16*) alloc((size_t)L_ * FF * D_ * 2);
  bf16*  w2T   = (bf16*) alloc((size_t)L_ * D_ * FF * 2);
  float* qkvB  = (float*)alloc((size_t)L_ * 3 * D_ * 4);
  float* pe    = (float*)alloc((size_t)B_ * D_ * 4);
  bf16*  h_b   = (bf16*) alloc((size_t)NTOK * D_ * 2);
  bf16*  delta = (bf16*) alloc((size_t)NTOK * D_ * 2);
  float* pooled= (float*)alloc((size_t)B_ * D_ * 4);
  float* part  = (float*)alloc((size_t)8 * NTOK * 4);
  bf16*  scratch = (bf16*)alloc((size_t)NTOK * FF * 2);
  bf16* qb  = scratch;
  bf16* kb  = scratch + (size_t)NTOK * D_;
  bf16* vTb = scratch + (size_t)2 * NTOK * D_;
  bf16* ob  = scratch + (size_t)3 * NTOK * D_;
  bf16* ffn1 = scratch;
  bf16* p0 = (bf16*)alloc((size_t)NTOK * D_ * 2);
  bf16* p1 = (bf16*)alloc((size_t)NTOK * D_ * 2);
  const bool canSplit = (off <= ws_size);
  (void)in_sizes; (void)n_in; (void)out_size;

  k_f2b<<<dim3(NTOK * IND / 1024), dim3(256), 0, stream>>>(x, x_bf);
  k_trans<<<dim3(D_ / 64, IND / 64, 1), dim3(256), 0, stream>>>(emb_w, embT, IND, D_, 0, 0);
  k_trans<<<dim3(D_ / 64, D_ / 64, L_), dim3(256), 0, stream>>>(Wq, qkvT,               D_, D_, (long)D_ * D_, (long)3 * D_ * D_);
  k_trans<<<dim3(D_ / 64, D_ / 64, L_), dim3(256), 0, stream>>>(Wk, qkvT + D_ * D_,     D_, D_, (long)D_ * D_, (long)3 * D_ * D_);
  k_trans<<<dim3(D_ / 64, D_ / 64, L_), dim3(256), 0, stream>>>(Wv, qkvT + 2 * D_ * D_, D_, D_, (long)D_ * D_, (long)3 * D_ * D_);
  k_trans<<<dim3(D_ / 64, D_ / 64, L_), dim3(256), 0, stream>>>(Wo, woT, D_, D_, (long)D_ * D_, (long)D_ * D_);
  k_trans<<<dim3(FF / 64, D_ / 64, L_), dim3(256), 0, stream>>>(W1, w1T, D_, FF, (long)D_ * FF, (long)FF * D_);
  k_trans<<<dim3(D_ / 64, FF / 64, L_), dim3(256), 0, stream>>>(W2, w2T, FF, D_, (long)FF * D_, (long)D_ * FF);
  k_pe<<<dim3(B_ * D_ / 256), dim3(256), 0, stream>>>(pe);
  k_packb<<<dim3(L_ * 3 * D_ / 256), dim3(256), 0, stream>>>(bq, bk, bv, qkvB);

  k_gemm<3><<<dim3(D_ / 128, NTOK / 128), dim3(256), 0, stream>>>(
      x_bf, embT, emb_b, nullptr, h_b, pe, NTOK, D_, IND);

  for (int l = 0; l < L_; ++l) {
    k_gemm256<2, 0><<<dim3(3 * D_ / 256, NTOK / 256), dim3(512), 0, stream>>>(
        h_b, qkvT + (size_t)l * 3 * D_ * D_, qkvB + l * 3 * D_,
        qb, vTb, nullptr, nullptr, NTOK, 3 * D_, D_);
    k_flash<<<dim3(S_ / 64, B_ * H_), dim3(256), 0, stream>>>(qb, kb, vTb, ob);
    if (canSplit) {
      k_gemm256<0, 1><<<dim3(D_ / 256, NTOK / 256, 2), dim3(512), 0, stream>>>(
          ob, woT + (size_t)l * D_ * D_, nullptr,
          nullptr, nullptr, p0, p1, NTOK, D_, D_);
      k_addln<1><<<dim3(NTOK), dim3(256), 0, stream>>>(
          h_b, nullptr, p0, p1, bo + l * D_, ln1s + l * D_, ln1b + l * D_, h_b);
    } else {
      k_gemm256<0, 0><<<dim3(D_ / 256, NTOK / 256), dim3(512), 0, stream>>>(
          ob, woT + (size_t)l * D_ * D_, bo + l * D_,
          delta, nullptr, nullptr, nullptr, NTOK, D_, D_);
      k_addln<0><<<dim3(NTOK), dim3(256), 0, stream>>>(
          h_b, delta, nullptr, nullptr, nullptr, ln1s + l * D_, ln1b + l * D_, h_b);
    }
    // FFN1 on the 32x32x16 MFMA variant (A/B vs k_gemm256 this round)
    k_gemm32<<<dim3(FF / 256, NTOK / 256), dim3(512), 0, stream>>>(
        h_b, w1T + (size_t)l * FF * D_, b1 + l * FF,
        ffn1, NTOK, FF, D_);
    if (canSplit) {
      k_gemm256<0, 1><<<dim3(D_ / 256, NTOK / 256, 2), dim3(512), 0, stream>>>(
          ffn1, w2T + (size_t)l * D_ * FF, nullptr,
          nullptr, nullptr, p0, p1, NTOK, D_, FF);
      k_addln<1><<<dim3(NTOK), dim3(256), 0, stream>>>(
          h_b, nullptr, p0, p1, b2 + l * D_, ln2s + l * D_, ln2b + l * D_, h_b);
    } else {
      k_gemm256<0, 0><<<dim3(D_ / 256, NTOK / 256), dim3(512), 0, stream>>>(
          ffn1, w2T + (size_t)l * D_ * FF, b2 + l * D_,
          delta, nullptr, nullptr, nullptr, NTOK, D_, FF);
      k_addln<0><<<dim3(NTOK), dim3(256), 0, stream>>>(
          h_b, delta, nullptr, nullptr, nullptr, ln2s + l * D_, ln2b + l * D_, h_b);
    }
  }

  k_pool1<<<dim3(NTOK / 256, 8), dim3(256), 0, stream>>>(h_b, part);
  k_pool2<<<dim3(NTOK / 256), dim3(256), 0, stream>>>(part, pooled);
  k_fc<<<dim3(B_ * 10), dim3(64), 0, stream>>>(pooled, fcw, fcb, (float*)d_out);
}